// Round 1
// baseline (12445.009 us; speedup 1.0000x reference)
//
#include <hip/hip_runtime.h>
#include <hip/hip_bf16.h>
#include <math.h>

#define B_ 16
#define S_ 256
#define T_ 800
#define V_ 256
#define D_ 512
#define M_ 80
#define H_ 1024
#define NH_ 4
#define HD_ 128
#define EH_ 256

__device__ __forceinline__ float sigf(float x) { return 1.f / (1.f + __expf(-x)); }

// ---------------- generic tiled fp32 GEMM: C = A(M,K) @ B(N,K)^T + bias -----
// epi: 0 = plain(+bias), 1 = conv BN+ReLU epilogue
__global__ __launch_bounds__(256) void gemm_tile(
    const float* __restrict__ A, int lda,
    const float* __restrict__ Bw,
    const float* __restrict__ bias,
    float* __restrict__ C, int ldc,
    int M, int N, int K, int epi,
    const float* __restrict__ cb, const float* __restrict__ gam,
    const float* __restrict__ bet, const float* __restrict__ mu,
    const float* __restrict__ va)
{
    __shared__ float As[16][68];
    __shared__ float Bs[16][68];
    const int tid = threadIdx.x;
    const int bm = blockIdx.y * 64, bn = blockIdx.x * 64;
    const int tx = tid & 15, ty = tid >> 4;
    const int lr = tid >> 2, lk = (tid & 3) * 4;

    float acc[4][4] = {};

    const float* Aptr = A + (size_t)(bm + lr) * lda + lk;
    const bool bvalid = (bn + lr) < N;
    const float* Bptr = Bw + (size_t)(bvalid ? (bn + lr) : 0) * K + lk;

    for (int k0 = 0; k0 < K; k0 += 16) {
        float4 av = *(const float4*)(Aptr + k0);
        float4 bw = bvalid ? *(const float4*)(Bptr + k0) : make_float4(0.f, 0.f, 0.f, 0.f);
        As[lk + 0][lr] = av.x; As[lk + 1][lr] = av.y; As[lk + 2][lr] = av.z; As[lk + 3][lr] = av.w;
        Bs[lk + 0][lr] = bw.x; Bs[lk + 1][lr] = bw.y; Bs[lk + 2][lr] = bw.z; Bs[lk + 3][lr] = bw.w;
        __syncthreads();
#pragma unroll
        for (int k = 0; k < 16; ++k) {
            float4 a = *(const float4*)&As[k][ty * 4];
            float4 b = *(const float4*)&Bs[k][tx * 4];
            acc[0][0] += a.x * b.x; acc[0][1] += a.x * b.y; acc[0][2] += a.x * b.z; acc[0][3] += a.x * b.w;
            acc[1][0] += a.y * b.x; acc[1][1] += a.y * b.y; acc[1][2] += a.y * b.z; acc[1][3] += a.y * b.w;
            acc[2][0] += a.z * b.x; acc[2][1] += a.z * b.y; acc[2][2] += a.z * b.z; acc[2][3] += a.z * b.w;
            acc[3][0] += a.w * b.x; acc[3][1] += a.w * b.y; acc[3][2] += a.w * b.z; acc[3][3] += a.w * b.w;
        }
        __syncthreads();
    }

    const int row0 = bm + ty * 4, col0 = bn + tx * 4;
#pragma unroll
    for (int i = 0; i < 4; ++i) {
#pragma unroll
        for (int j = 0; j < 4; ++j) {
            int cc = col0 + j;
            if (cc < N) {
                float v = acc[i][j];
                if (bias) v += bias[cc];
                if (epi == 1) {
                    float x = v + cb[cc];
                    v = fmaxf(0.f, gam[cc] * (x - mu[cc]) * rsqrtf(va[cc] + 1e-5f) + bet[cc]);
                }
                C[(size_t)(row0 + i) * ldc + cc] = v;
            }
        }
    }
}

// ---------------- elementwise / data-movement kernels ----------------------
__global__ void embed_k(const int* __restrict__ txt, const float* __restrict__ emb,
                        float* __restrict__ xs)
{
    int idx = blockIdx.x * 256 + threadIdx.x;
    if (idx >= B_ * S_ * D_) return;
    int bs = idx >> 9, dd = idx & 511;
    xs[idx] = emb[(size_t)txt[bs] * D_ + dd];
}

__global__ void im2col_k(const float* __restrict__ in, float* __restrict__ out)
{
    int idx = blockIdx.x * 256 + threadIdx.x;
    if (idx >= B_ * S_ * 2560) return;
    int r = idx / 2560, cc = idx % 2560;
    int din = cc / 5, kk = cc % 5;
    int b = r >> 8, s = r & 255;
    int sp = s + kk - 2;
    float v = 0.f;
    if (sp >= 0 && sp < S_) v = in[((size_t)b * S_ + sp) * D_ + din];
    out[idx] = v;
}

__global__ void transp_k(const float* __restrict__ in, float* __restrict__ out)
{
    // in (B,S,D) -> out (S,B,D)
    int idx = blockIdx.x * 256 + threadIdx.x;
    if (idx >= B_ * S_ * D_) return;
    int d = idx & 511;
    int sb = idx >> 9;
    int s = sb / B_, b = sb % B_;
    out[idx] = in[((size_t)b * S_ + s) * D_ + d];
}

__global__ void decin_k(const float* __restrict__ mel, float* __restrict__ di)
{
    int idx = blockIdx.x * 256 + threadIdx.x;
    if (idx >= B_ * T_ * M_) return;
    int m = idx / M_, j = idx % M_;
    int b = m / T_, t = m % T_;
    di[idx] = (t == 0) ? 0.f : mel[((size_t)b * T_ + t - 1) * M_ + j];
}

__global__ void xcat_copy_k(const float* __restrict__ di, float* __restrict__ xcat)
{
    int idx = blockIdx.x * 256 + threadIdx.x;
    if (idx >= B_ * T_ * M_) return;
    int m = idx / M_, j = idx % M_;
    xcat[(size_t)m * 592 + 512 + j] = di[idx];
}

__global__ void dec_cell(const float* __restrict__ g, float* __restrict__ h, int rows)
{
    int idx = blockIdx.x * 256 + threadIdx.x;
    if (idx >= rows * H_) return;
    int r = idx >> 10, j = idx & 1023;
    const float* gr = g + (size_t)r * 4096;
    float ig = sigf(gr[j]);
    float gg = tanhf(gr[2048 + j]);
    float og = sigf(gr[3072 + j]);
    h[idx] = og * tanhf(ig * gg);
}

__global__ __launch_bounds__(256) void stop_head(
    const float* __restrict__ h2, const float* __restrict__ sw,
    const float* __restrict__ sb, float* __restrict__ out)
{
    int row = blockIdx.x * 4 + (threadIdx.x >> 6);
    int lane = threadIdx.x & 63;
    const float* hr = h2 + (size_t)row * H_;
    float acc = 0.f;
#pragma unroll
    for (int i = 0; i < H_; i += 64) acc += hr[i + lane] * sw[i + lane];
    for (int off = 32; off; off >>= 1) acc += __shfl_xor(acc, off);
    if (lane == 0) out[row] = acc + sb[0];
}

// ---------------- encoder LSTM scan (per (batch, direction) workgroup) -----
__global__ __launch_bounds__(256) void lstm_scan(
    const float* __restrict__ gi_f, const float* __restrict__ gi_b,
    const float* __restrict__ Wf, const float* __restrict__ Wb,
    float* __restrict__ enc)
{
    const int b = blockIdx.x;
    const int dir = blockIdx.y;
    const float* gi = dir ? gi_b : gi_f;
    const float* W  = dir ? Wb : Wf;
    const int t = threadIdx.x;     // hidden index 0..255

    __shared__ float hs[EH_];
    const float* w0 = W + (size_t)t * EH_;
    const float* w1 = W + (size_t)(EH_ + t) * EH_;
    const float* w2 = W + (size_t)(2 * EH_ + t) * EH_;
    const float* w3 = W + (size_t)(3 * EH_ + t) * EH_;

    float c = 0.f;
    hs[t] = 0.f;
    __syncthreads();

    for (int step = 0; step < S_; ++step) {
        int s = dir ? (S_ - 1 - step) : step;
        const float* gr = gi + ((size_t)s * B_ + b) * (4 * EH_);
        float di = gr[t], df = gr[EH_ + t], dg = gr[2 * EH_ + t], do_ = gr[3 * EH_ + t];
#pragma unroll 4
        for (int kk = 0; kk < EH_; kk += 4) {
            float4 h4 = *(const float4*)&hs[kk];
            float4 a0 = *(const float4*)(w0 + kk);
            float4 a1 = *(const float4*)(w1 + kk);
            float4 a2 = *(const float4*)(w2 + kk);
            float4 a3 = *(const float4*)(w3 + kk);
            di  += h4.x * a0.x + h4.y * a0.y + h4.z * a0.z + h4.w * a0.w;
            df  += h4.x * a1.x + h4.y * a1.y + h4.z * a1.z + h4.w * a1.w;
            dg  += h4.x * a2.x + h4.y * a2.y + h4.z * a2.z + h4.w * a2.w;
            do_ += h4.x * a3.x + h4.y * a3.y + h4.z * a3.z + h4.w * a3.w;
        }
        float ig = sigf(di), fg = sigf(df), gg = tanhf(dg), og = sigf(do_);
        c = fg * c + ig * gg;
        float hnew = og * tanhf(c);
        __syncthreads();
        hs[t] = hnew;
        __syncthreads();
        enc[((size_t)b * S_ + s) * D_ + dir * EH_ + t] = hnew;
    }
}

// ---------------- attention ------------------------------------------------
__global__ __launch_bounds__(256) void attn_scores(
    const float* __restrict__ q, const float* __restrict__ k, float* __restrict__ attn)
{
    const int t = blockIdx.x, h = blockIdx.y, b = blockIdx.z;
    const int s = threadIdx.x;
    __shared__ float qrow[HD_];
    __shared__ float red[4];
    if (s < HD_) qrow[s] = q[(((size_t)b * T_ + t) * NH_ + h) * HD_ + s];
    __syncthreads();

    const float* krow = k + (((size_t)b * S_ + s) * NH_ + h) * HD_;
    float d = 0.f;
#pragma unroll
    for (int i = 0; i < HD_; i += 4) {
        float4 kk = *(const float4*)(krow + i);
        d += qrow[i] * kk.x + qrow[i + 1] * kk.y + qrow[i + 2] * kk.z + qrow[i + 3] * kk.w;
    }
    d *= 0.08838834764831843f;   // 1/sqrt(128)

    float m = d;
    for (int off = 32; off; off >>= 1) m = fmaxf(m, __shfl_xor(m, off));
    if ((s & 63) == 0) red[s >> 6] = m;
    __syncthreads();
    m = fmaxf(fmaxf(red[0], red[1]), fmaxf(red[2], red[3]));
    float p = __expf(d - m);
    float sum = p;
    for (int off = 32; off; off >>= 1) sum += __shfl_xor(sum, off);
    __syncthreads();
    if ((s & 63) == 0) red[s >> 6] = sum;
    __syncthreads();
    sum = red[0] + red[1] + red[2] + red[3];
    attn[(((size_t)b * NH_ + h) * T_ + t) * S_ + s] = p / sum;
}

__global__ __launch_bounds__(128) void attn_ctx(
    const float* __restrict__ attn, const float* __restrict__ v, float* __restrict__ ctx)
{
    const int t = blockIdx.x, h = blockIdx.y, b = blockIdx.z;
    const int d = threadIdx.x;
    __shared__ float at[S_];
    const float* arow = attn + (((size_t)b * NH_ + h) * T_ + t) * S_;
    at[d] = arow[d];
    at[d + 128] = arow[d + 128];
    __syncthreads();
    const float* vp = v + ((size_t)b * S_ * NH_ + h) * HD_ + d;
    float acc = 0.f;
#pragma unroll 4
    for (int s = 0; s < S_; ++s) acc += at[s] * vp[(size_t)s * D_];
    ctx[(((size_t)b * T_ + t) * NH_ + h) * HD_ + d] = acc;
}

// ---------------- host orchestration --------------------------------------
static inline void launch_gemm(hipStream_t stream,
                               const float* A, int lda, const float* Bw, const float* bias,
                               float* C, int ldc, int M, int N, int K, int epi = 0,
                               const float* cb = nullptr, const float* g = nullptr,
                               const float* be = nullptr, const float* mu = nullptr,
                               const float* va = nullptr)
{
    dim3 grid((N + 63) / 64, M / 64);
    gemm_tile<<<grid, 256, 0, stream>>>(A, lda, Bw, bias, C, ldc, M, N, K, epi, cb, g, be, mu, va);
}

extern "C" void kernel_launch(void* const* d_in, const int* in_sizes, int n_in,
                              void* d_out, int out_size, void* d_ws, size_t ws_size,
                              hipStream_t stream)
{
    const int*   text   = (const int*)d_in[0];
    const float* mel_t  = (const float*)d_in[1];
    const float* emb    = (const float*)d_in[2];
    const float* conv_w = (const float*)d_in[3];
    const float* conv_b = (const float*)d_in[4];
    const float* bn_g   = (const float*)d_in[5];
    const float* bn_b   = (const float*)d_in[6];
    const float* bn_m   = (const float*)d_in[7];
    const float* bn_v   = (const float*)d_in[8];
    const float* Wih_f  = (const float*)d_in[9];
    const float* Whh_f  = (const float*)d_in[10];
    const float* b_f    = (const float*)d_in[11];
    const float* Wih_b  = (const float*)d_in[12];
    const float* Whh_b  = (const float*)d_in[13];
    const float* b_b    = (const float*)d_in[14];
    const float* Wq     = (const float*)d_in[15];
    const float* bq     = (const float*)d_in[16];
    const float* Wk     = (const float*)d_in[17];
    const float* bk     = (const float*)d_in[18];
    const float* Wv     = (const float*)d_in[19];
    const float* bv     = (const float*)d_in[20];
    const float* Wo     = (const float*)d_in[21];
    const float* bo     = (const float*)d_in[22];
    const float* Wih1   = (const float*)d_in[23];
    const float* b1     = (const float*)d_in[24];
    const float* Wih2   = (const float*)d_in[25];
    const float* b2     = (const float*)d_in[26];
    const float* melW   = (const float*)d_in[27];
    const float* melb   = (const float*)d_in[28];
    const float* stopW  = (const float*)d_in[29];
    const float* stopb  = (const float*)d_in[30];
    float* out = (float*)d_out;

    float* ws = (float*)d_ws;
    size_t off = 0;
    auto take = [&](size_t n) { float* p = ws + off; off += n; return p; };
    float* big   = take(13107200); // im2col (10.5M) | attn scores (13.1M) | h1/h2 (13.1M)
    float* P0    = take(2097152);  // (B,S,D) ping
    float* P1    = take(2097152);  // (B,S,D) pong
    float* gi_f  = take(4194304);  // gates-in fwd | later k,v
    float* gi_b  = take(4194304);  // gates-in bwd
    float* enc   = take(2097152);  // (B,S,512)
    float* qx    = take(7577600);  // q (6.55M) | xcat (7.58M)
    float* decin = take(1024000);  // (B,T,80)
    float* ctx   = take(6553600);  // (B,T,512)
    float* gates = take(6553600);  // chunk 1600 x 4096
    (void)ws_size; (void)in_sizes; (void)n_in; (void)out_size;

    // ---- encoder: embedding + 3 convs ----
    embed_k<<<(B_ * S_ * D_ + 255) / 256, 256, 0, stream>>>(text, emb, P0);
    float* cin = P0;
    float* cout = P1;
    for (int l = 0; l < 3; ++l) {
        im2col_k<<<(B_ * S_ * 2560 + 255) / 256, 256, 0, stream>>>(cin, big);
        launch_gemm(stream, big, 2560, conv_w + (size_t)l * D_ * 2560, nullptr,
                    cout, D_, B_ * S_, D_, 2560, 1,
                    conv_b + l * D_, bn_g + l * D_, bn_b + l * D_, bn_m + l * D_, bn_v + l * D_);
        float* tmp = cin; cin = cout; cout = tmp;
    }
    // cin == conv output (B,S,D). Transpose to (S,B,D) into cout.
    transp_k<<<(B_ * S_ * D_ + 255) / 256, 256, 0, stream>>>(cin, cout);
    float* xsT = cout;

    // ---- encoder LSTM: input projections + scan ----
    launch_gemm(stream, xsT, D_, Wih_f, b_f, gi_f, 4 * EH_, S_ * B_, 4 * EH_, D_);
    launch_gemm(stream, xsT, D_, Wih_b, b_b, gi_b, 4 * EH_, S_ * B_, 4 * EH_, D_);
    lstm_scan<<<dim3(B_, 2), 256, 0, stream>>>(gi_f, gi_b, Whh_f, Whh_b, enc);

    // ---- attention projections ----
    float* kbuf = gi_f;
    float* vbuf = gi_f + 2097152;
    launch_gemm(stream, enc, D_, Wk, bk, kbuf, D_, B_ * S_, D_, D_);
    launch_gemm(stream, enc, D_, Wv, bv, vbuf, D_, B_ * S_, D_, D_);
    decin_k<<<(B_ * T_ * M_ + 255) / 256, 256, 0, stream>>>(mel_t, decin);
    float* qbuf = qx;
    launch_gemm(stream, decin, M_, Wq, bq, qbuf, D_, B_ * T_, D_, M_);

    // ---- attention ----
    attn_scores<<<dim3(T_, NH_, B_), 256, 0, stream>>>(qbuf, kbuf, big);
    attn_ctx<<<dim3(T_, NH_, B_), 128, 0, stream>>>(big, vbuf, ctx);

    // ---- output projection into xcat[:, :512], dec_in into xcat[:, 512:] ----
    float* xcat = qx;
    launch_gemm(stream, ctx, D_, Wo, bo, xcat, 592, B_ * T_, D_, D_);
    xcat_copy_k<<<(B_ * T_ * M_ + 255) / 256, 256, 0, stream>>>(decin, xcat);

    // ---- decoder cells (chunked) ----
    float* h = big;
    const int MC = 1600;
    for (int c0 = 0; c0 < B_ * T_; c0 += MC) {
        launch_gemm(stream, xcat + (size_t)c0 * 592, 592, Wih1, b1, gates, 4096, MC, 4096, 592);
        dec_cell<<<(MC * H_ + 255) / 256, 256, 0, stream>>>(gates, h + (size_t)c0 * H_, MC);
    }
    for (int c0 = 0; c0 < B_ * T_; c0 += MC) {
        launch_gemm(stream, h + (size_t)c0 * H_, H_, Wih2, b2, gates, 4096, MC, 4096, 1024);
        dec_cell<<<(MC * H_ + 255) / 256, 256, 0, stream>>>(gates, h + (size_t)c0 * H_, MC);
    }

    // ---- output heads ----
    launch_gemm(stream, h, H_, melW, melb, out, M_, B_ * T_, M_, H_);
    stop_head<<<(B_ * T_) / 4, 256, 0, stream>>>(h, stopW, stopb, out + (size_t)B_ * T_ * M_);
}

// Round 2
// 9207.870 us; speedup vs baseline: 1.3516x; 1.3516x over previous
//
#include <hip/hip_runtime.h>
#include <hip/hip_bf16.h>
#include <math.h>

#define B_ 16
#define S_ 256
#define T_ 800
#define V_ 256
#define D_ 512
#define M_ 80
#define H_ 1024
#define NH_ 4
#define HD_ 128
#define EH_ 256

using bf16x8 = __attribute__((ext_vector_type(8))) short;
using f32x4  = __attribute__((ext_vector_type(4))) float;

__device__ __forceinline__ float sigf(float x) { return 1.f / (1.f + __expf(-x)); }

__device__ __forceinline__ unsigned short f2bf(float f) {
    unsigned int u = __float_as_uint(f);
    unsigned int r = (u + 0x7FFFu + ((u >> 16) & 1u)) >> 16;
    return (unsigned short)r;
}

__device__ __forceinline__ void gl_lds16(const unsigned short* g, unsigned short* l) {
    __builtin_amdgcn_global_load_lds((const __attribute__((address_space(1))) void*)g,
                                     (__attribute__((address_space(3))) void*)l, 16, 0, 0);
}

// ---------------- MFMA bf16 GEMM: C = A(M,K) @ B(N,K)^T, M%128==0, N%128==0, K%32==0
// epi: 0 = fp32 out (+bias), 1 = conv BN+ReLU fp32 out, 2 = bf16 out (+bias)
__global__ __launch_bounds__(256) void gemm_mfma(
    const unsigned short* __restrict__ A, const unsigned short* __restrict__ Bw,
    void* __restrict__ Cv, const float* __restrict__ bias,
    int M, int N, int K, int ldc, int epi,
    const float* __restrict__ cb, const float* __restrict__ gam,
    const float* __restrict__ bet, const float* __restrict__ mu,
    const float* __restrict__ va)
{
    __shared__ unsigned short As[4096];
    __shared__ unsigned short Bs[4096];
    const int tid = threadIdx.x, w = tid >> 6, lane = tid & 63;
    const int bm = blockIdx.y * 128, bn = blockIdx.x * 128;
    const int wr = w >> 1, wc = w & 1;

    f32x4 acc[4][4];
#pragma unroll
    for (int m = 0; m < 4; ++m)
#pragma unroll
        for (int n = 0; n < 4; ++n) acc[m][n] = (f32x4){0.f, 0.f, 0.f, 0.f};

    const int r0 = w * 16 + (lane >> 2);
    const int k8 = (lane & 3) * 8;
    const unsigned short* Ag = A + (size_t)(bm + r0) * K + k8;
    const unsigned short* Bg = Bw + (size_t)(bn + r0) * K + k8;
    unsigned short* Al = As + w * 512;
    unsigned short* Bl = Bs + w * 512;

    for (int k0 = 0; k0 < K; k0 += 32) {
        __syncthreads();
        gl_lds16(Ag + k0, Al);
        gl_lds16(Ag + (size_t)64 * K + k0, Al + 2048);
        gl_lds16(Bg + k0, Bl);
        gl_lds16(Bg + (size_t)64 * K + k0, Bl + 2048);
        __syncthreads();
        bf16x8 a[4], b[4];
#pragma unroll
        for (int m = 0; m < 4; ++m)
            a[m] = *(const bf16x8*)(As + (wr * 64 + m * 16 + (lane & 15)) * 32 + (lane >> 4) * 8);
#pragma unroll
        for (int n = 0; n < 4; ++n)
            b[n] = *(const bf16x8*)(Bs + (wc * 64 + n * 16 + (lane & 15)) * 32 + (lane >> 4) * 8);
#pragma unroll
        for (int m = 0; m < 4; ++m)
#pragma unroll
            for (int n = 0; n < 4; ++n)
                acc[m][n] = __builtin_amdgcn_mfma_f32_16x16x32_bf16(a[m], b[n], acc[m][n], 0, 0, 0);
    }

    const int cr = (lane >> 4) * 4, ccol = lane & 15;
#pragma unroll
    for (int m = 0; m < 4; ++m)
#pragma unroll
        for (int n = 0; n < 4; ++n) {
            const int col = bn + wc * 64 + n * 16 + ccol;
            const float bv = bias ? bias[col] : 0.f;
#pragma unroll
            for (int j = 0; j < 4; ++j) {
                const int row = bm + wr * 64 + m * 16 + cr + j;
                float v = acc[m][n][j] + bv;
                if (epi == 1) {
                    float x = v + cb[col];
                    v = fmaxf(0.f, gam[col] * (x - mu[col]) * rsqrtf(va[col] + 1e-5f) + bet[col]);
                }
                if (epi == 2) ((unsigned short*)Cv)[(size_t)row * ldc + col] = f2bf(v);
                else          ((float*)Cv)[(size_t)row * ldc + col] = v;
            }
        }
}

// ---------------- fp32 tiled GEMM (kept for mel head, N=80) ----------------
__global__ __launch_bounds__(256) void gemm_tile(
    const float* __restrict__ A, int lda,
    const float* __restrict__ Bw,
    const float* __restrict__ bias,
    float* __restrict__ C, int ldc,
    int M, int N, int K)
{
    __shared__ float As[16][68];
    __shared__ float Bs[16][68];
    const int tid = threadIdx.x;
    const int bm = blockIdx.y * 64, bn = blockIdx.x * 64;
    const int tx = tid & 15, ty = tid >> 4;
    const int lr = tid >> 2, lk = (tid & 3) * 4;

    float acc[4][4] = {};

    const float* Aptr = A + (size_t)(bm + lr) * lda + lk;
    const bool bvalid = (bn + lr) < N;
    const float* Bptr = Bw + (size_t)(bvalid ? (bn + lr) : 0) * K + lk;

    for (int k0 = 0; k0 < K; k0 += 16) {
        float4 av = *(const float4*)(Aptr + k0);
        float4 bw = bvalid ? *(const float4*)(Bptr + k0) : make_float4(0.f, 0.f, 0.f, 0.f);
        As[lk + 0][lr] = av.x; As[lk + 1][lr] = av.y; As[lk + 2][lr] = av.z; As[lk + 3][lr] = av.w;
        Bs[lk + 0][lr] = bw.x; Bs[lk + 1][lr] = bw.y; Bs[lk + 2][lr] = bw.z; Bs[lk + 3][lr] = bw.w;
        __syncthreads();
#pragma unroll
        for (int k = 0; k < 16; ++k) {
            float4 a = *(const float4*)&As[k][ty * 4];
            float4 b = *(const float4*)&Bs[k][tx * 4];
            acc[0][0] += a.x * b.x; acc[0][1] += a.x * b.y; acc[0][2] += a.x * b.z; acc[0][3] += a.x * b.w;
            acc[1][0] += a.y * b.x; acc[1][1] += a.y * b.y; acc[1][2] += a.y * b.z; acc[1][3] += a.y * b.w;
            acc[2][0] += a.z * b.x; acc[2][1] += a.z * b.y; acc[2][2] += a.z * b.z; acc[2][3] += a.z * b.w;
            acc[3][0] += a.w * b.x; acc[3][1] += a.w * b.y; acc[3][2] += a.w * b.z; acc[3][3] += a.w * b.w;
        }
        __syncthreads();
    }

    const int row0 = bm + ty * 4, col0 = bn + tx * 4;
#pragma unroll
    for (int i = 0; i < 4; ++i)
#pragma unroll
        for (int j = 0; j < 4; ++j) {
            int cc = col0 + j;
            if (cc < N) {
                float v = acc[i][j];
                if (bias) v += bias[cc];
                C[(size_t)(row0 + i) * ldc + cc] = v;
            }
        }
}

// ---------------- elementwise / conversion kernels -------------------------
__global__ void embed_k(const int* __restrict__ txt, const float* __restrict__ emb,
                        float* __restrict__ xs)
{
    int idx = blockIdx.x * 256 + threadIdx.x;
    if (idx >= B_ * S_ * D_) return;
    int bs = idx >> 9, dd = idx & 511;
    xs[idx] = emb[(size_t)txt[bs] * D_ + dd];
}

__global__ void im2col_bf(const float* __restrict__ in, unsigned short* __restrict__ out)
{
    int idx = blockIdx.x * 256 + threadIdx.x;
    if (idx >= B_ * S_ * 2560) return;
    int r = idx / 2560, cc = idx % 2560;
    int din = cc / 5, kk = cc % 5;
    int b = r >> 8, s = r & 255;
    int sp = s + kk - 2;
    float v = (sp >= 0 && sp < S_) ? in[((size_t)b * S_ + sp) * D_ + din] : 0.f;
    out[idx] = f2bf(v);
}

__global__ void transp_bf(const float* __restrict__ in, unsigned short* __restrict__ out)
{
    // in (B,S,D) fp32 -> out (S,B,D) bf16
    int idx = blockIdx.x * 256 + threadIdx.x;
    if (idx >= B_ * S_ * D_) return;
    int d = idx & 511;
    int sb = idx >> 9;
    int s = sb >> 4, b = sb & 15;
    out[idx] = f2bf(in[((size_t)b * S_ + s) * D_ + d]);
}

__global__ void cvt_bf(const float* __restrict__ in, unsigned short* __restrict__ out,
                       int rows, int Kin, int Kout)
{
    int idx = blockIdx.x * 256 + threadIdx.x;
    if (idx >= rows * Kout) return;
    int r = idx / Kout, k = idx - r * Kout;
    out[idx] = (k < Kin) ? f2bf(in[(size_t)r * Kin + k]) : 0;
}

// permuted decoder weights: drop f gate; order [i; g; o]
__global__ void cvt_w1(const float* __restrict__ W, unsigned short* __restrict__ out)
{
    int idx = blockIdx.x * 256 + threadIdx.x;
    if (idx >= 3072 * 608) return;
    int n = idx / 608, k = idx - n * 608;
    int orig = (n < 1024) ? n : n + 1024;
    out[idx] = (k < 592) ? f2bf(W[(size_t)orig * 592 + k]) : 0;
}

__global__ void cvt_w2(const float* __restrict__ W, unsigned short* __restrict__ out)
{
    int idx = blockIdx.x * 256 + threadIdx.x;
    if (idx >= 3072 * 1024) return;
    int n = idx >> 10, k = idx & 1023;
    int orig = (n < 1024) ? n : n + 1024;
    out[idx] = f2bf(W[(size_t)orig * 1024 + k]);
}

__global__ void decin_k2(const float* __restrict__ mel, unsigned short* __restrict__ din,
                         unsigned short* __restrict__ xcat)
{
    int idx = blockIdx.x * 256 + threadIdx.x;
    if (idx >= B_ * T_ * 96) return;
    int r = idx / 96, j = idx - r * 96;
    int b = r / T_, t = r - b * T_;
    float v = (j < M_ && t > 0) ? mel[((size_t)b * T_ + t - 1) * M_ + j] : 0.f;
    unsigned short bv = f2bf(v);
    din[(size_t)r * 96 + j] = bv;
    xcat[(size_t)r * 608 + 512 + j] = bv;
}

__global__ void dec_cell1(const float* __restrict__ g, const float* __restrict__ b1,
                          unsigned short* __restrict__ h, int rows)
{
    int idx = blockIdx.x * 256 + threadIdx.x;
    if (idx >= rows * H_) return;
    int r = idx >> 10, j = idx & 1023;
    const float* gr = g + (size_t)r * 3072;
    float ig = sigf(gr[j] + b1[j]);
    float gg = tanhf(gr[1024 + j] + b1[2048 + j]);
    float og = sigf(gr[2048 + j] + b1[3072 + j]);
    h[idx] = f2bf(og * tanhf(ig * gg));
}

__global__ void dec_cell2(const float* __restrict__ g, const float* __restrict__ b2,
                          float* __restrict__ h, int rows)
{
    int idx = blockIdx.x * 256 + threadIdx.x;
    if (idx >= rows * H_) return;
    int r = idx >> 10, j = idx & 1023;
    const float* gr = g + (size_t)r * 3072;
    float ig = sigf(gr[j] + b2[j]);
    float gg = tanhf(gr[1024 + j] + b2[2048 + j]);
    float og = sigf(gr[2048 + j] + b2[3072 + j]);
    h[idx] = og * tanhf(ig * gg);
}

__global__ __launch_bounds__(256) void stop_head(
    const float* __restrict__ h2, const float* __restrict__ sw,
    const float* __restrict__ sb, float* __restrict__ out)
{
    int row = blockIdx.x * 4 + (threadIdx.x >> 6);
    int lane = threadIdx.x & 63;
    const float* hr = h2 + (size_t)row * H_;
    float acc = 0.f;
#pragma unroll
    for (int i = 0; i < H_; i += 64) acc += hr[i + lane] * sw[i + lane];
    for (int off = 32; off; off >>= 1) acc += __shfl_xor(acc, off);
    if (lane == 0) out[row] = acc + sb[0];
}

// ---------------- encoder LSTM scan: 1 block of 1024 threads per (b,dir) ---
__global__ __launch_bounds__(1024) void lstm_scan2(
    const float* __restrict__ gi_f, const float* __restrict__ gi_b,
    const float* __restrict__ Wf, const float* __restrict__ Wb,
    unsigned short* __restrict__ enc)
{
    const int b = blockIdx.x & 15, dir = blockIdx.x >> 4;
    const float* gi = dir ? gi_b : gi_f;
    const float* W  = dir ? Wb : Wf;
    const int g = threadIdx.x;          // gate row 0..1023 (i,f,g,o each 256)
    __shared__ float hs[EH_];
    __shared__ float gsum[1024];
    const float* wrow = W + (size_t)g * EH_;

    float c = 0.f;
    if (g < EH_) hs[g] = 0.f;
    __syncthreads();

    for (int step = 0; step < S_; ++step) {
        const int s = dir ? (S_ - 1 - step) : step;
        float d = gi[((size_t)s * B_ + b) * 1024 + g];   // includes bias
        float a0 = 0.f, a1 = 0.f, a2 = 0.f, a3 = 0.f;
#pragma unroll 4
        for (int kk = 0; kk < EH_; kk += 16) {
            float4 w0 = *(const float4*)(wrow + kk);
            float4 w1 = *(const float4*)(wrow + kk + 4);
            float4 w2 = *(const float4*)(wrow + kk + 8);
            float4 w3 = *(const float4*)(wrow + kk + 12);
            float4 h0 = *(const float4*)&hs[kk];
            float4 h1 = *(const float4*)&hs[kk + 4];
            float4 h2 = *(const float4*)&hs[kk + 8];
            float4 h3 = *(const float4*)&hs[kk + 12];
            a0 += w0.x * h0.x + w0.y * h0.y + w0.z * h0.z + w0.w * h0.w;
            a1 += w1.x * h1.x + w1.y * h1.y + w1.z * h1.z + w1.w * h1.w;
            a2 += w2.x * h2.x + w2.y * h2.y + w2.z * h2.z + w2.w * h2.w;
            a3 += w3.x * h3.x + w3.y * h3.y + w3.z * h3.z + w3.w * h3.w;
        }
        d += (a0 + a1) + (a2 + a3);
        gsum[g] = d;
        __syncthreads();
        if (g < EH_) {
            float ig = sigf(gsum[g]);
            float fg = sigf(gsum[EH_ + g]);
            float gg = tanhf(gsum[2 * EH_ + g]);
            float og = sigf(gsum[3 * EH_ + g]);
            c = fg * c + ig * gg;
            float hn = og * tanhf(c);
            hs[g] = hn;
            enc[((size_t)b * S_ + s) * D_ + dir * EH_ + g] = f2bf(hn);
        }
        __syncthreads();
    }
}

// ---------------- attention ------------------------------------------------
__global__ __launch_bounds__(256) void attn_scores(
    const float* __restrict__ q, const float* __restrict__ k, float* __restrict__ attn)
{
    const int t = blockIdx.x, h = blockIdx.y, b = blockIdx.z;
    const int s = threadIdx.x;
    __shared__ float qrow[HD_];
    __shared__ float red[4];
    if (s < HD_) qrow[s] = q[(((size_t)b * T_ + t) * NH_ + h) * HD_ + s];
    __syncthreads();

    const float* krow = k + (((size_t)b * S_ + s) * NH_ + h) * HD_;
    float d = 0.f;
#pragma unroll
    for (int i = 0; i < HD_; i += 4) {
        float4 kk = *(const float4*)(krow + i);
        d += qrow[i] * kk.x + qrow[i + 1] * kk.y + qrow[i + 2] * kk.z + qrow[i + 3] * kk.w;
    }
    d *= 0.08838834764831843f;

    float m = d;
    for (int off = 32; off; off >>= 1) m = fmaxf(m, __shfl_xor(m, off));
    if ((s & 63) == 0) red[s >> 6] = m;
    __syncthreads();
    m = fmaxf(fmaxf(red[0], red[1]), fmaxf(red[2], red[3]));
    float p = __expf(d - m);
    float sum = p;
    for (int off = 32; off; off >>= 1) sum += __shfl_xor(sum, off);
    __syncthreads();
    if ((s & 63) == 0) red[s >> 6] = sum;
    __syncthreads();
    sum = red[0] + red[1] + red[2] + red[3];
    attn[(((size_t)b * NH_ + h) * T_ + t) * S_ + s] = p / sum;
}

__global__ __launch_bounds__(128) void attn_ctx(
    const float* __restrict__ attn, const float* __restrict__ v, unsigned short* __restrict__ ctx)
{
    const int t = blockIdx.x, h = blockIdx.y, b = blockIdx.z;
    const int d = threadIdx.x;
    __shared__ float at[S_];
    const float* arow = attn + (((size_t)b * NH_ + h) * T_ + t) * S_;
    at[d] = arow[d];
    at[d + 128] = arow[d + 128];
    __syncthreads();
    const float* vp = v + ((size_t)b * S_ * NH_ + h) * HD_ + d;
    float acc = 0.f;
#pragma unroll 4
    for (int s = 0; s < S_; ++s) acc += at[s] * vp[(size_t)s * D_];
    ctx[(((size_t)b * T_ + t) * NH_ + h) * HD_ + d] = f2bf(acc);
}

// ---------------- host orchestration --------------------------------------
static inline void launch_mfma(hipStream_t st, const unsigned short* A, const unsigned short* B,
                               void* C, const float* bias, int M, int N, int K, int ldc, int epi = 0,
                               const float* cb = nullptr, const float* gam = nullptr,
                               const float* bet = nullptr, const float* mu = nullptr,
                               const float* va = nullptr)
{
    dim3 grid(N / 128, M / 128);
    gemm_mfma<<<grid, 256, 0, st>>>(A, B, C, bias, M, N, K, ldc, epi, cb, gam, bet, mu, va);
}

extern "C" void kernel_launch(void* const* d_in, const int* in_sizes, int n_in,
                              void* d_out, int out_size, void* d_ws, size_t ws_size,
                              hipStream_t stream)
{
    const int*   text   = (const int*)d_in[0];
    const float* mel_t  = (const float*)d_in[1];
    const float* emb    = (const float*)d_in[2];
    const float* conv_w = (const float*)d_in[3];
    const float* conv_b = (const float*)d_in[4];
    const float* bn_g   = (const float*)d_in[5];
    const float* bn_b   = (const float*)d_in[6];
    const float* bn_m   = (const float*)d_in[7];
    const float* bn_v   = (const float*)d_in[8];
    const float* Wih_f  = (const float*)d_in[9];
    const float* Whh_f  = (const float*)d_in[10];
    const float* b_f    = (const float*)d_in[11];
    const float* Wih_b  = (const float*)d_in[12];
    const float* Whh_b  = (const float*)d_in[13];
    const float* b_b    = (const float*)d_in[14];
    const float* Wq     = (const float*)d_in[15];
    const float* bq     = (const float*)d_in[16];
    const float* Wk     = (const float*)d_in[17];
    const float* bk     = (const float*)d_in[18];
    const float* Wv     = (const float*)d_in[19];
    const float* bv     = (const float*)d_in[20];
    const float* Wo     = (const float*)d_in[21];
    const float* bo     = (const float*)d_in[22];
    const float* Wih1   = (const float*)d_in[23];
    const float* b1     = (const float*)d_in[24];
    const float* Wih2   = (const float*)d_in[25];
    const float* b2     = (const float*)d_in[26];
    const float* melW   = (const float*)d_in[27];
    const float* melb   = (const float*)d_in[28];
    const float* stopW  = (const float*)d_in[29];
    const float* stopb  = (const float*)d_in[30];
    float* out = (float*)d_out;
    (void)in_sizes; (void)n_in; (void)out_size; (void)ws_size;

    float* ws = (float*)d_ws;
    float* big  = ws;                       // 13107200 f: im2col_bf | scores | h2
    float* pool = ws + 13107200;

    // pool offsets (floats)
    float*          gi_f   = pool + 0;
    float*          gi_b   = pool + 4194304;
    unsigned short* enc_bf = (unsigned short*)(pool + 8388608);
    float*          P0     = pool + 9437184;
    float*          P1     = pool + 11534336;
    unsigned short* xsT    = (unsigned short*)(pool + 13631488);
    float*          kbuf   = pool + 0;          // after lstm
    float*          vbuf   = pool + 2097152;
    float*          qbuf   = pool + 9437184;    // ..15990784
    unsigned short* dinb   = (unsigned short*)(pool + 15990784);
    unsigned short* ctxb   = (unsigned short*)(pool + 16605184); // ..19881984
    float*          gates  = pool + 0;          // phase D, ..9830400
    unsigned short* h1b    = (unsigned short*)(pool + 9830400);  // ..16384000
    unsigned short* xcat   = (unsigned short*)(pool + 19881984); // ..23773184
    float*          WB     = pool + 23773184;
    unsigned short* cWc = (unsigned short*)(WB + 0);        // conv weights 1536x2560
    unsigned short* cWif= (unsigned short*)(WB + 1966080);  // 1024x512
    unsigned short* cWib= (unsigned short*)(WB + 2228224);
    unsigned short* cWk = (unsigned short*)(WB + 2490368);  // 512x512
    unsigned short* cWv = (unsigned short*)(WB + 2621440);
    unsigned short* cWq = (unsigned short*)(WB + 2752512);  // 512x96
    unsigned short* cWo = (unsigned short*)(WB + 2785280);  // 512x512
    unsigned short* cW1 = (unsigned short*)(WB + 2916352);  // 3072x608
    unsigned short* cW2 = (unsigned short*)(WB + 3850240);  // 3072x1024

    auto ceil256 = [](int n) { return (n + 255) / 256; };

    // ---- weight conversions (independent, upfront) ----
    cvt_bf<<<ceil256(1536 * 2560), 256, 0, stream>>>(conv_w, cWc, 1536, 2560, 2560);
    cvt_bf<<<ceil256(1024 * 512), 256, 0, stream>>>(Wih_f, cWif, 1024, 512, 512);
    cvt_bf<<<ceil256(1024 * 512), 256, 0, stream>>>(Wih_b, cWib, 1024, 512, 512);
    cvt_bf<<<ceil256(512 * 512), 256, 0, stream>>>(Wk, cWk, 512, 512, 512);
    cvt_bf<<<ceil256(512 * 512), 256, 0, stream>>>(Wv, cWv, 512, 512, 512);
    cvt_bf<<<ceil256(512 * 96), 256, 0, stream>>>(Wq, cWq, 512, 80, 96);
    cvt_bf<<<ceil256(512 * 512), 256, 0, stream>>>(Wo, cWo, 512, 512, 512);
    cvt_w1<<<ceil256(3072 * 608), 256, 0, stream>>>(Wih1, cW1);
    cvt_w2<<<ceil256(3072 * 1024), 256, 0, stream>>>(Wih2, cW2);

    // ---- encoder: embedding + 3 convs (MFMA, BN+ReLU fused) ----
    embed_k<<<ceil256(B_ * S_ * D_), 256, 0, stream>>>(text, emb, P0);
    float* cin = P0;
    float* cout = P1;
    for (int l = 0; l < 3; ++l) {
        im2col_bf<<<ceil256(B_ * S_ * 2560), 256, 0, stream>>>(cin, (unsigned short*)big);
        launch_mfma(stream, (unsigned short*)big, cWc + (size_t)l * 512 * 2560,
                    cout, nullptr, B_ * S_, 512, 2560, 512, 1,
                    conv_b + l * 512, bn_g + l * 512, bn_b + l * 512, bn_m + l * 512, bn_v + l * 512);
        float* tmp = cin; cin = cout; cout = tmp;
    }
    transp_bf<<<ceil256(B_ * S_ * D_), 256, 0, stream>>>(cin, xsT);

    // ---- encoder LSTM ----
    launch_mfma(stream, xsT, cWif, gi_f, b_f, S_ * B_, 1024, 512, 1024);
    launch_mfma(stream, xsT, cWib, gi_b, b_b, S_ * B_, 1024, 512, 1024);
    lstm_scan2<<<32, 1024, 0, stream>>>(gi_f, gi_b, Whh_f, Whh_b, enc_bf);

    // ---- attention projections ----
    launch_mfma(stream, enc_bf, cWk, kbuf, bk, B_ * S_, 512, 512, 512);
    launch_mfma(stream, enc_bf, cWv, vbuf, bv, B_ * S_, 512, 512, 512);
    decin_k2<<<ceil256(B_ * T_ * 96), 256, 0, stream>>>(mel_t, dinb, xcat);
    launch_mfma(stream, dinb, cWq, qbuf, bq, B_ * T_, 512, 96, 512);

    // ---- attention ----
    attn_scores<<<dim3(T_, NH_, B_), 256, 0, stream>>>(qbuf, kbuf, big);
    attn_ctx<<<dim3(T_, NH_, B_), 128, 0, stream>>>(big, vbuf, ctxb);

    // ---- Wo projection -> xcat cols [0,512) as bf16 (cols [512,608) from decin_k2) ----
    launch_mfma(stream, ctxb, cWo, xcat, bo, B_ * T_, 512, 512, 608, 2);

    // ---- decoder cells (f-gate dropped; N=3072 = [i;g;o]) ----
    float* h2 = big;
    const int MC = 3200;
    for (int c0 = 0; c0 < B_ * T_; c0 += MC) {
        launch_mfma(stream, xcat + (size_t)c0 * 608, cW1, gates, nullptr, MC, 3072, 608, 3072);
        dec_cell1<<<ceil256(MC * H_), 256, 0, stream>>>(gates, b1, h1b + (size_t)c0 * H_, MC);
    }
    for (int c0 = 0; c0 < B_ * T_; c0 += MC) {
        launch_mfma(stream, h1b + (size_t)c0 * H_, cW2, gates, nullptr, MC, 3072, 1024, 3072);
        dec_cell2<<<ceil256(MC * H_), 256, 0, stream>>>(gates, b2, h2 + (size_t)c0 * H_, MC);
    }

    // ---- output heads ----
    {
        dim3 grid((80 + 63) / 64, (B_ * T_) / 64);
        gemm_tile<<<grid, 256, 0, stream>>>(h2, 1024, melW, melb, out, 80, B_ * T_, 80, 1024);
    }
    stop_head<<<(B_ * T_) / 4, 256, 0, stream>>>(h2, stopW, stopb, out + (size_t)B_ * T_ * M_);
}

// Round 3
// 3395.972 us; speedup vs baseline: 3.6646x; 2.7114x over previous
//
#include <hip/hip_runtime.h>
#include <hip/hip_bf16.h>
#include <math.h>

#define B_ 16
#define S_ 256
#define T_ 800
#define V_ 256
#define D_ 512
#define M_ 80
#define H_ 1024
#define NH_ 4
#define HD_ 128
#define EH_ 256

using bf16x8 = __attribute__((ext_vector_type(8))) short;
using f32x4  = __attribute__((ext_vector_type(4))) float;
typedef _Float16 half8 __attribute__((ext_vector_type(8)));

__device__ __forceinline__ float sigf(float x) { return 1.f / (1.f + __expf(-x)); }

__device__ __forceinline__ unsigned short f2bf(float f) {
    unsigned int u = __float_as_uint(f);
    unsigned int r = (u + 0x7FFFu + ((u >> 16) & 1u)) >> 16;
    return (unsigned short)r;
}

__device__ __forceinline__ void gl_lds16(const unsigned short* g, unsigned short* l) {
    __builtin_amdgcn_global_load_lds((const __attribute__((address_space(1))) void*)g,
                                     (__attribute__((address_space(3))) void*)l, 16, 0, 0);
}

// ---------------- MFMA bf16 GEMM: C = A(M,K) @ B(N,K)^T, M%128==0, N%128==0, K%32==0
__global__ __launch_bounds__(256) void gemm_mfma(
    const unsigned short* __restrict__ A, const unsigned short* __restrict__ Bw,
    void* __restrict__ Cv, const float* __restrict__ bias,
    int M, int N, int K, int ldc, int epi,
    const float* __restrict__ cb, const float* __restrict__ gam,
    const float* __restrict__ bet, const float* __restrict__ mu,
    const float* __restrict__ va)
{
    __shared__ unsigned short As[4096];
    __shared__ unsigned short Bs[4096];
    const int tid = threadIdx.x, w = tid >> 6, lane = tid & 63;
    const int bm = blockIdx.y * 128, bn = blockIdx.x * 128;
    const int wr = w >> 1, wc = w & 1;

    f32x4 acc[4][4];
#pragma unroll
    for (int m = 0; m < 4; ++m)
#pragma unroll
        for (int n = 0; n < 4; ++n) acc[m][n] = (f32x4){0.f, 0.f, 0.f, 0.f};

    const int r0 = w * 16 + (lane >> 2);
    const int k8 = (lane & 3) * 8;
    const unsigned short* Ag = A + (size_t)(bm + r0) * K + k8;
    const unsigned short* Bg = Bw + (size_t)(bn + r0) * K + k8;
    unsigned short* Al = As + w * 512;
    unsigned short* Bl = Bs + w * 512;

    for (int k0 = 0; k0 < K; k0 += 32) {
        __syncthreads();
        gl_lds16(Ag + k0, Al);
        gl_lds16(Ag + (size_t)64 * K + k0, Al + 2048);
        gl_lds16(Bg + k0, Bl);
        gl_lds16(Bg + (size_t)64 * K + k0, Bl + 2048);
        __syncthreads();
        bf16x8 a[4], b[4];
#pragma unroll
        for (int m = 0; m < 4; ++m)
            a[m] = *(const bf16x8*)(As + (wr * 64 + m * 16 + (lane & 15)) * 32 + (lane >> 4) * 8);
#pragma unroll
        for (int n = 0; n < 4; ++n)
            b[n] = *(const bf16x8*)(Bs + (wc * 64 + n * 16 + (lane & 15)) * 32 + (lane >> 4) * 8);
#pragma unroll
        for (int m = 0; m < 4; ++m)
#pragma unroll
            for (int n = 0; n < 4; ++n)
                acc[m][n] = __builtin_amdgcn_mfma_f32_16x16x32_bf16(a[m], b[n], acc[m][n], 0, 0, 0);
    }

    const int cr = (lane >> 4) * 4, ccol = lane & 15;
#pragma unroll
    for (int m = 0; m < 4; ++m)
#pragma unroll
        for (int n = 0; n < 4; ++n) {
            const int col = bn + wc * 64 + n * 16 + ccol;
            const float bv = bias ? bias[col] : 0.f;
#pragma unroll
            for (int j = 0; j < 4; ++j) {
                const int row = bm + wr * 64 + m * 16 + cr + j;
                float v = acc[m][n][j] + bv;
                if (epi == 1) {
                    float x = v + cb[col];
                    v = fmaxf(0.f, gam[col] * (x - mu[col]) * rsqrtf(va[col] + 1e-5f) + bet[col]);
                }
                if (epi == 2) ((unsigned short*)Cv)[(size_t)row * ldc + col] = f2bf(v);
                else          ((float*)Cv)[(size_t)row * ldc + col] = v;
            }
        }
}

// ---------------- fp32 tiled GEMM (mel head, N=80) --------------------------
__global__ __launch_bounds__(256) void gemm_tile(
    const float* __restrict__ A, int lda,
    const float* __restrict__ Bw,
    const float* __restrict__ bias,
    float* __restrict__ C, int ldc,
    int M, int N, int K)
{
    __shared__ float As[16][68];
    __shared__ float Bs[16][68];
    const int tid = threadIdx.x;
    const int bm = blockIdx.y * 64, bn = blockIdx.x * 64;
    const int tx = tid & 15, ty = tid >> 4;
    const int lr = tid >> 2, lk = (tid & 3) * 4;

    float acc[4][4] = {};

    const float* Aptr = A + (size_t)(bm + lr) * lda + lk;
    const bool bvalid = (bn + lr) < N;
    const float* Bptr = Bw + (size_t)(bvalid ? (bn + lr) : 0) * K + lk;

    for (int k0 = 0; k0 < K; k0 += 16) {
        float4 av = *(const float4*)(Aptr + k0);
        float4 bw = bvalid ? *(const float4*)(Bptr + k0) : make_float4(0.f, 0.f, 0.f, 0.f);
        As[lk + 0][lr] = av.x; As[lk + 1][lr] = av.y; As[lk + 2][lr] = av.z; As[lk + 3][lr] = av.w;
        Bs[lk + 0][lr] = bw.x; Bs[lk + 1][lr] = bw.y; Bs[lk + 2][lr] = bw.z; Bs[lk + 3][lr] = bw.w;
        __syncthreads();
#pragma unroll
        for (int k = 0; k < 16; ++k) {
            float4 a = *(const float4*)&As[k][ty * 4];
            float4 b = *(const float4*)&Bs[k][tx * 4];
            acc[0][0] += a.x * b.x; acc[0][1] += a.x * b.y; acc[0][2] += a.x * b.z; acc[0][3] += a.x * b.w;
            acc[1][0] += a.y * b.x; acc[1][1] += a.y * b.y; acc[1][2] += a.y * b.z; acc[1][3] += a.y * b.w;
            acc[2][0] += a.z * b.x; acc[2][1] += a.z * b.y; acc[2][2] += a.z * b.z; acc[2][3] += a.z * b.w;
            acc[3][0] += a.w * b.x; acc[3][1] += a.w * b.y; acc[3][2] += a.w * b.z; acc[3][3] += a.w * b.w;
        }
        __syncthreads();
    }

    const int row0 = bm + ty * 4, col0 = bn + tx * 4;
#pragma unroll
    for (int i = 0; i < 4; ++i)
#pragma unroll
        for (int j = 0; j < 4; ++j) {
            int cc = col0 + j;
            if (cc < N) {
                float v = acc[i][j];
                if (bias) v += bias[cc];
                C[(size_t)(row0 + i) * ldc + cc] = v;
            }
        }
}

// ---------------- elementwise / conversion kernels -------------------------
__global__ void embed_k(const int* __restrict__ txt, const float* __restrict__ emb,
                        float* __restrict__ xs)
{
    int idx = blockIdx.x * 256 + threadIdx.x;
    if (idx >= B_ * S_ * D_) return;
    int bs = idx >> 9, dd = idx & 511;
    xs[idx] = emb[(size_t)txt[bs] * D_ + dd];
}

__global__ void im2col_bf(const float* __restrict__ in, unsigned short* __restrict__ out)
{
    int idx = blockIdx.x * 256 + threadIdx.x;
    if (idx >= B_ * S_ * 2560) return;
    int r = idx / 2560, cc = idx % 2560;
    int din = cc / 5, kk = cc % 5;
    int b = r >> 8, s = r & 255;
    int sp = s + kk - 2;
    float v = (sp >= 0 && sp < S_) ? in[((size_t)b * S_ + sp) * D_ + din] : 0.f;
    out[idx] = f2bf(v);
}

__global__ void transp_bf(const float* __restrict__ in, unsigned short* __restrict__ out)
{
    int idx = blockIdx.x * 256 + threadIdx.x;
    if (idx >= B_ * S_ * D_) return;
    int d = idx & 511;
    int sb = idx >> 9;
    int s = sb >> 4, b = sb & 15;
    out[idx] = f2bf(in[((size_t)b * S_ + s) * D_ + d]);
}

__global__ void cvt_bf(const float* __restrict__ in, unsigned short* __restrict__ out,
                       int rows, int Kin, int Kout)
{
    int idx = blockIdx.x * 256 + threadIdx.x;
    if (idx >= rows * Kout) return;
    int r = idx / Kout, k = idx - r * Kout;
    out[idx] = (k < Kin) ? f2bf(in[(size_t)r * Kin + k]) : 0;
}

__global__ void cvt_w1(const float* __restrict__ W, unsigned short* __restrict__ out)
{
    int idx = blockIdx.x * 256 + threadIdx.x;
    if (idx >= 3072 * 608) return;
    int n = idx / 608, k = idx - n * 608;
    int orig = (n < 1024) ? n : n + 1024;
    out[idx] = (k < 592) ? f2bf(W[(size_t)orig * 592 + k]) : 0;
}

__global__ void cvt_w2(const float* __restrict__ W, unsigned short* __restrict__ out)
{
    int idx = blockIdx.x * 256 + threadIdx.x;
    if (idx >= 3072 * 1024) return;
    int n = idx >> 10, k = idx & 1023;
    int orig = (n < 1024) ? n : n + 1024;
    out[idx] = f2bf(W[(size_t)orig * 1024 + k]);
}

__global__ void decin_k2(const float* __restrict__ mel, unsigned short* __restrict__ din,
                         unsigned short* __restrict__ xcat)
{
    int idx = blockIdx.x * 256 + threadIdx.x;
    if (idx >= B_ * T_ * 96) return;
    int r = idx / 96, j = idx - r * 96;
    int b = r / T_, t = r - b * T_;
    float v = (j < M_ && t > 0) ? mel[((size_t)b * T_ + t - 1) * M_ + j] : 0.f;
    unsigned short bv = f2bf(v);
    din[(size_t)r * 96 + j] = bv;
    xcat[(size_t)r * 608 + 512 + j] = bv;
}

__global__ void dec_cell1(const float* __restrict__ g, const float* __restrict__ b1,
                          unsigned short* __restrict__ h, int rows)
{
    int idx = blockIdx.x * 256 + threadIdx.x;
    if (idx >= rows * H_) return;
    int r = idx >> 10, j = idx & 1023;
    const float* gr = g + (size_t)r * 3072;
    float ig = sigf(gr[j] + b1[j]);
    float gg = tanhf(gr[1024 + j] + b1[2048 + j]);
    float og = sigf(gr[2048 + j] + b1[3072 + j]);
    h[idx] = f2bf(og * tanhf(ig * gg));
}

__global__ void dec_cell2(const float* __restrict__ g, const float* __restrict__ b2,
                          float* __restrict__ h, int rows)
{
    int idx = blockIdx.x * 256 + threadIdx.x;
    if (idx >= rows * H_) return;
    int r = idx >> 10, j = idx & 1023;
    const float* gr = g + (size_t)r * 3072;
    float ig = sigf(gr[j] + b2[j]);
    float gg = tanhf(gr[1024 + j] + b2[2048 + j]);
    float og = sigf(gr[2048 + j] + b2[3072 + j]);
    h[idx] = og * tanhf(ig * gg);
}

__global__ __launch_bounds__(256) void stop_head(
    const float* __restrict__ h2, const float* __restrict__ sw,
    const float* __restrict__ sb, float* __restrict__ out)
{
    int row = blockIdx.x * 4 + (threadIdx.x >> 6);
    int lane = threadIdx.x & 63;
    const float* hr = h2 + (size_t)row * H_;
    float acc = 0.f;
#pragma unroll
    for (int i = 0; i < H_; i += 64) acc += hr[i + lane] * sw[i + lane];
    for (int off = 32; off; off >>= 1) acc += __shfl_xor(acc, off);
    if (lane == 0) out[row] = acc + sb[0];
}

// ---------------- persistent grid-synced LSTM ------------------------------
// 32 blocks = 2 dirs x 16 hidden-groups; block owns 16 hidden units x 4 gates.
// W rows live in VGPRs as f16 MFMA B-fragments (wave w = gate w).
// Per step: mfma(h16x256, W64x256^T) -> gate exchange in LDS -> wave0 c/h
// update -> h broadcast via global f16 stage + per-step atomic barrier.
__global__ __launch_bounds__(256) void lstm_persist(
    const float* __restrict__ gi_f, const float* __restrict__ gi_b,
    const float* __restrict__ Wf, const float* __restrict__ Wb,
    unsigned short* __restrict__ enc,     // bf16 (B,S,512)
    _Float16* __restrict__ hstage,        // [2][16][256]
    int* __restrict__ cnt)                // [2][256]
{
    const int blk = blockIdx.x;
    const int dir = blk >> 4, g = blk & 15;
    const float* gi = dir ? gi_b : gi_f;
    const float* W  = dir ? Wb : Wf;
    const int tid = threadIdx.x, wv = tid >> 6, lane = tid & 63;
    const int l15 = lane & 15, bq = lane >> 4;   // l15: hid (B/C) or batch (A)

    __shared__ _Float16 h_lds[16][264];          // [batch][hid], +8 pad
    __shared__ float exch[3][64][4];             // gate tiles f,g,o

    // --- preload W fragments (once): wave wv = gate wv, rows g*16 + 0..15 ---
    half8 bfr[8];
    {
        const float* wrow = W + (size_t)(wv * 256 + g * 16 + l15) * 256;
#pragma unroll
        for (int ks = 0; ks < 8; ++ks) {
            const int k0 = ks * 32 + bq * 8;
            half8 hv;
#pragma unroll
            for (int j = 0; j < 8; ++j) hv[j] = (_Float16)wrow[k0 + j];
            bfr[ks] = hv;
        }
    }
    for (int i = tid; i < 16 * 264; i += 256) ((_Float16*)h_lds)[i] = (_Float16)0.f;
    __syncthreads();

    float c0 = 0.f, c1 = 0.f, c2 = 0.f, c3 = 0.f;   // wave0 state, batches bq*4+j
    int* mycnt = cnt + dir * 256;

    for (int step = 0; step < 256; ++step) {
        const int s = dir ? (255 - step) : step;
        // gi prefetch: own gate column for 4 batches
        const int gcol = wv * 256 + g * 16 + l15;
        const float gi0 = gi[((size_t)s * 16 + bq * 4 + 0) * 1024 + gcol];
        const float gi1 = gi[((size_t)s * 16 + bq * 4 + 1) * 1024 + gcol];
        const float gi2 = gi[((size_t)s * 16 + bq * 4 + 2) * 1024 + gcol];
        const float gi3 = gi[((size_t)s * 16 + bq * 4 + 3) * 1024 + gcol];

        f32x4 acc = (f32x4){0.f, 0.f, 0.f, 0.f};
#pragma unroll
        for (int ks = 0; ks < 8; ++ks) {
            half8 a = *(const half8*)&h_lds[l15][ks * 32 + bq * 8];
            acc = __builtin_amdgcn_mfma_f32_16x16x32_f16(a, bfr[ks], acc, 0, 0, 0);
        }
        acc[0] += gi0; acc[1] += gi1; acc[2] += gi2; acc[3] += gi3;
        if (wv) *(f32x4*)&exch[wv - 1][lane][0] = acc;
        __syncthreads();

        if (wv == 0) {
            const f32x4 af = *(const f32x4*)&exch[0][lane][0];
            const f32x4 ag = *(const f32x4*)&exch[1][lane][0];
            const f32x4 ao = *(const f32x4*)&exch[2][lane][0];
            float hv[4];
            {
                float i0 = sigf(acc[0]), f0 = sigf(af[0]), g0 = tanhf(ag[0]), o0 = sigf(ao[0]);
                c0 = f0 * c0 + i0 * g0; hv[0] = o0 * tanhf(c0);
                float i1 = sigf(acc[1]), f1 = sigf(af[1]), g1 = tanhf(ag[1]), o1 = sigf(ao[1]);
                c1 = f1 * c1 + i1 * g1; hv[1] = o1 * tanhf(c1);
                float i2 = sigf(acc[2]), f2 = sigf(af[2]), g2 = tanhf(ag[2]), o2 = sigf(ao[2]);
                c2 = f2 * c2 + i2 * g2; hv[2] = o2 * tanhf(c2);
                float i3 = sigf(acc[3]), f3 = sigf(af[3]), g3 = tanhf(ag[3]), o3 = sigf(ao[3]);
                c3 = f3 * c3 + i3 * g3; hv[3] = o3 * tanhf(c3);
            }
            const int hg = g * 16 + l15;
#pragma unroll
            for (int j = 0; j < 4; ++j) {
                const int b = bq * 4 + j;
                hstage[((size_t)dir * 16 + b) * 256 + hg] = (_Float16)hv[j];
                enc[((size_t)b * S_ + s) * D_ + dir * 256 + hg] = f2bf(hv[j]);
            }
        }
        // ---- per-step barrier among the 16 blocks of this direction ----
        if (tid == 0) {
            __threadfence();
            __hip_atomic_fetch_add(&mycnt[step], 1, __ATOMIC_RELEASE, __HIP_MEMORY_SCOPE_AGENT);
            while (__hip_atomic_load(&mycnt[step], __ATOMIC_ACQUIRE, __HIP_MEMORY_SCOPE_AGENT) < 16)
                __builtin_amdgcn_s_sleep(2);
        }
        __syncthreads();
        __threadfence();
        // ---- reload full h into LDS ----
        {
            const int b = tid >> 4, c16 = tid & 15;
            const _Float16* src = hstage + ((size_t)dir * 16 + b) * 256 + c16 * 16;
            const float4 v0 = *(const float4*)(src);
            const float4 v1 = *(const float4*)(src + 8);
            *(float4*)&h_lds[b][c16 * 16] = v0;
            *(float4*)&h_lds[b][c16 * 16 + 8] = v1;
        }
        __syncthreads();
    }
}

// ---------------- attention ------------------------------------------------
__global__ __launch_bounds__(256) void attn_scores(
    const float* __restrict__ q, const float* __restrict__ k, float* __restrict__ attn)
{
    const int t = blockIdx.x, h = blockIdx.y, b = blockIdx.z;
    const int s = threadIdx.x;
    __shared__ float qrow[HD_];
    __shared__ float red[4];
    if (s < HD_) qrow[s] = q[(((size_t)b * T_ + t) * NH_ + h) * HD_ + s];
    __syncthreads();

    const float* krow = k + (((size_t)b * S_ + s) * NH_ + h) * HD_;
    float d = 0.f;
#pragma unroll
    for (int i = 0; i < HD_; i += 4) {
        float4 kk = *(const float4*)(krow + i);
        d += qrow[i] * kk.x + qrow[i + 1] * kk.y + qrow[i + 2] * kk.z + qrow[i + 3] * kk.w;
    }
    d *= 0.08838834764831843f;

    float m = d;
    for (int off = 32; off; off >>= 1) m = fmaxf(m, __shfl_xor(m, off));
    if ((s & 63) == 0) red[s >> 6] = m;
    __syncthreads();
    m = fmaxf(fmaxf(red[0], red[1]), fmaxf(red[2], red[3]));
    float p = __expf(d - m);
    float sum = p;
    for (int off = 32; off; off >>= 1) sum += __shfl_xor(sum, off);
    __syncthreads();
    if ((s & 63) == 0) red[s >> 6] = sum;
    __syncthreads();
    sum = red[0] + red[1] + red[2] + red[3];
    attn[(((size_t)b * NH_ + h) * T_ + t) * S_ + s] = p / sum;
}

__global__ __launch_bounds__(128) void attn_ctx(
    const float* __restrict__ attn, const float* __restrict__ v, unsigned short* __restrict__ ctx)
{
    const int t = blockIdx.x, h = blockIdx.y, b = blockIdx.z;
    const int d = threadIdx.x;
    __shared__ float at[S_];
    const float* arow = attn + (((size_t)b * NH_ + h) * T_ + t) * S_;
    at[d] = arow[d];
    at[d + 128] = arow[d + 128];
    __syncthreads();
    const float* vp = v + ((size_t)b * S_ * NH_ + h) * HD_ + d;
    float acc = 0.f;
#pragma unroll 4
    for (int s = 0; s < S_; ++s) acc += at[s] * vp[(size_t)s * D_];
    ctx[(((size_t)b * T_ + t) * NH_ + h) * HD_ + d] = f2bf(acc);
}

// ---------------- host orchestration --------------------------------------
static inline void launch_mfma(hipStream_t st, const unsigned short* A, const unsigned short* B,
                               void* C, const float* bias, int M, int N, int K, int ldc, int epi = 0,
                               const float* cb = nullptr, const float* gam = nullptr,
                               const float* bet = nullptr, const float* mu = nullptr,
                               const float* va = nullptr)
{
    dim3 grid(N / 128, M / 128);
    gemm_mfma<<<grid, 256, 0, st>>>(A, B, C, bias, M, N, K, ldc, epi, cb, gam, bet, mu, va);
}

extern "C" void kernel_launch(void* const* d_in, const int* in_sizes, int n_in,
                              void* d_out, int out_size, void* d_ws, size_t ws_size,
                              hipStream_t stream)
{
    const int*   text   = (const int*)d_in[0];
    const float* mel_t  = (const float*)d_in[1];
    const float* emb    = (const float*)d_in[2];
    const float* conv_w = (const float*)d_in[3];
    const float* conv_b = (const float*)d_in[4];
    const float* bn_g   = (const float*)d_in[5];
    const float* bn_b   = (const float*)d_in[6];
    const float* bn_m   = (const float*)d_in[7];
    const float* bn_v   = (const float*)d_in[8];
    const float* Wih_f  = (const float*)d_in[9];
    const float* Whh_f  = (const float*)d_in[10];
    const float* b_f    = (const float*)d_in[11];
    const float* Wih_b  = (const float*)d_in[12];
    const float* Whh_b  = (const float*)d_in[13];
    const float* b_b    = (const float*)d_in[14];
    const float* Wq     = (const float*)d_in[15];
    const float* bq     = (const float*)d_in[16];
    const float* Wk     = (const float*)d_in[17];
    const float* bk     = (const float*)d_in[18];
    const float* Wv     = (const float*)d_in[19];
    const float* bv     = (const float*)d_in[20];
    const float* Wo     = (const float*)d_in[21];
    const float* bo     = (const float*)d_in[22];
    const float* Wih1   = (const float*)d_in[23];
    const float* b1     = (const float*)d_in[24];
    const float* Wih2   = (const float*)d_in[25];
    const float* b2     = (const float*)d_in[26];
    const float* melW   = (const float*)d_in[27];
    const float* melb   = (const float*)d_in[28];
    const float* stopW  = (const float*)d_in[29];
    const float* stopb  = (const float*)d_in[30];
    float* out = (float*)d_out;
    (void)in_sizes; (void)n_in; (void)out_size; (void)ws_size;

    float* ws = (float*)d_ws;
    float* big  = ws;                       // 13107200 f: im2col_bf | scores | h2
    float* pool = ws + 13107200;

    // LSTM barrier counters + h stage live in the quiet tail of `big`
    // (im2col uses floats [0, 5.25M); attn scores only after lstm is done)
    int*      cnt    = (int*)(ws + 6000000);            // [2][256]
    _Float16* hstage = (_Float16*)(ws + 6000000 + 512); // [2][16][256]

    float*          gi_f   = pool + 0;
    float*          gi_b   = pool + 4194304;
    unsigned short* enc_bf = (unsigned short*)(pool + 8388608);
    float*          P0     = pool + 9437184;
    float*          P1     = pool + 11534336;
    unsigned short* xsT    = (unsigned short*)(pool + 13631488);
    float*          kbuf   = pool + 0;          // after lstm
    float*          vbuf   = pool + 2097152;
    float*          qbuf   = pool + 9437184;
    unsigned short* dinb   = (unsigned short*)(pool + 15990784);
    unsigned short* ctxb   = (unsigned short*)(pool + 16605184);
    float*          gates  = pool + 0;          // phase D
    unsigned short* h1b    = (unsigned short*)(pool + 9830400);
    unsigned short* xcat   = (unsigned short*)(pool + 19881984);
    float*          WB     = pool + 23773184;
    unsigned short* cWc = (unsigned short*)(WB + 0);
    unsigned short* cWif= (unsigned short*)(WB + 1966080);
    unsigned short* cWib= (unsigned short*)(WB + 2228224);
    unsigned short* cWk = (unsigned short*)(WB + 2490368);
    unsigned short* cWv = (unsigned short*)(WB + 2621440);
    unsigned short* cWq = (unsigned short*)(WB + 2752512);
    unsigned short* cWo = (unsigned short*)(WB + 2785280);
    unsigned short* cW1 = (unsigned short*)(WB + 2916352);
    unsigned short* cW2 = (unsigned short*)(WB + 3850240);

    auto ceil256 = [](int n) { return (n + 255) / 256; };

    // ---- reset barrier counters + zero h0 stage (18,432 B) ----
    hipMemsetAsync(cnt, 0, 512 * 4 + 2 * 16 * 256 * 2, stream);

    // ---- weight conversions ----
    cvt_bf<<<ceil256(1536 * 2560), 256, 0, stream>>>(conv_w, cWc, 1536, 2560, 2560);
    cvt_bf<<<ceil256(1024 * 512), 256, 0, stream>>>(Wih_f, cWif, 1024, 512, 512);
    cvt_bf<<<ceil256(1024 * 512), 256, 0, stream>>>(Wih_b, cWib, 1024, 512, 512);
    cvt_bf<<<ceil256(512 * 512), 256, 0, stream>>>(Wk, cWk, 512, 512, 512);
    cvt_bf<<<ceil256(512 * 512), 256, 0, stream>>>(Wv, cWv, 512, 512, 512);
    cvt_bf<<<ceil256(512 * 96), 256, 0, stream>>>(Wq, cWq, 512, 80, 96);
    cvt_bf<<<ceil256(512 * 512), 256, 0, stream>>>(Wo, cWo, 512, 512, 512);
    cvt_w1<<<ceil256(3072 * 608), 256, 0, stream>>>(Wih1, cW1);
    cvt_w2<<<ceil256(3072 * 1024), 256, 0, stream>>>(Wih2, cW2);

    // ---- encoder: embedding + 3 convs ----
    embed_k<<<ceil256(B_ * S_ * D_), 256, 0, stream>>>(text, emb, P0);
    float* cin = P0;
    float* cout = P1;
    for (int l = 0; l < 3; ++l) {
        im2col_bf<<<ceil256(B_ * S_ * 2560), 256, 0, stream>>>(cin, (unsigned short*)big);
        launch_mfma(stream, (unsigned short*)big, cWc + (size_t)l * 512 * 2560,
                    cout, nullptr, B_ * S_, 512, 2560, 512, 1,
                    conv_b + l * 512, bn_g + l * 512, bn_b + l * 512, bn_m + l * 512, bn_v + l * 512);
        float* tmp = cin; cin = cout; cout = tmp;
    }
    transp_bf<<<ceil256(B_ * S_ * D_), 256, 0, stream>>>(cin, xsT);

    // ---- encoder LSTM: input projections + persistent scan ----
    launch_mfma(stream, xsT, cWif, gi_f, b_f, S_ * B_, 1024, 512, 1024);
    launch_mfma(stream, xsT, cWib, gi_b, b_b, S_ * B_, 1024, 512, 1024);
    lstm_persist<<<32, 256, 0, stream>>>(gi_f, gi_b, Whh_f, Whh_b, enc_bf, hstage, cnt);

    // ---- attention projections ----
    launch_mfma(stream, enc_bf, cWk, kbuf, bk, B_ * S_, 512, 512, 512);
    launch_mfma(stream, enc_bf, cWv, vbuf, bv, B_ * S_, 512, 512, 512);
    decin_k2<<<ceil256(B_ * T_ * 96), 256, 0, stream>>>(mel_t, dinb, xcat);
    launch_mfma(stream, dinb, cWq, qbuf, bq, B_ * T_, 512, 96, 512);

    // ---- attention ----
    attn_scores<<<dim3(T_, NH_, B_), 256, 0, stream>>>(qbuf, kbuf, big);
    attn_ctx<<<dim3(T_, NH_, B_), 128, 0, stream>>>(big, vbuf, ctxb);

    // ---- Wo projection -> xcat[:, :512) bf16 ----
    launch_mfma(stream, ctxb, cWo, xcat, bo, B_ * T_, 512, 512, 608, 2);

    // ---- decoder cells ----
    float* h2 = big;
    const int MC = 3200;
    for (int c0 = 0; c0 < B_ * T_; c0 += MC) {
        launch_mfma(stream, xcat + (size_t)c0 * 608, cW1, gates, nullptr, MC, 3072, 608, 3072);
        dec_cell1<<<ceil256(MC * H_), 256, 0, stream>>>(gates, b1, h1b + (size_t)c0 * H_, MC);
    }
    for (int c0 = 0; c0 < B_ * T_; c0 += MC) {
        launch_mfma(stream, h1b + (size_t)c0 * H_, cW2, gates, nullptr, MC, 3072, 1024, 3072);
        dec_cell2<<<ceil256(MC * H_), 256, 0, stream>>>(gates, b2, h2 + (size_t)c0 * H_, MC);
    }

    // ---- output heads ----
    {
        dim3 grid((80 + 63) / 64, (B_ * T_) / 64);
        gemm_tile<<<grid, 256, 0, stream>>>(h2, 1024, melW, melb, out, 80, B_ * T_, 80, 1024);
    }
    stop_head<<<(B_ * T_) / 4, 256, 0, stream>>>(h2, stopW, stopb, out + (size_t)B_ * T_ * M_);
}

// Round 4
// 2914.426 us; speedup vs baseline: 4.2701x; 1.1652x over previous
//
#include <hip/hip_runtime.h>
#include <hip/hip_bf16.h>
#include <math.h>

#define B_ 16
#define S_ 256
#define T_ 800
#define V_ 256
#define D_ 512
#define M_ 80
#define H_ 1024
#define NH_ 4
#define HD_ 128
#define EH_ 256

using bf16x8 = __attribute__((ext_vector_type(8))) short;
using f32x4  = __attribute__((ext_vector_type(4))) float;
typedef _Float16 half8 __attribute__((ext_vector_type(8)));

__device__ __forceinline__ float sigf(float x) { return 1.f / (1.f + __expf(-x)); }
__device__ __forceinline__ float tanhfast(float x) {
    float e = __expf(2.f * x);
    return 1.f - 2.f / (e + 1.f);
}

__device__ __forceinline__ unsigned short f2bf(float f) {
    unsigned int u = __float_as_uint(f);
    unsigned int r = (u + 0x7FFFu + ((u >> 16) & 1u)) >> 16;
    return (unsigned short)r;
}

__device__ __forceinline__ void gl_lds16(const unsigned short* g, unsigned short* l) {
    __builtin_amdgcn_global_load_lds((const __attribute__((address_space(1))) void*)g,
                                     (__attribute__((address_space(3))) void*)l, 16, 0, 0);
}

// ---------------- MFMA bf16 GEMM: C = A(M,K) @ B(N,K)^T --------------------
// epi: 0 fp32 out(+bias), 1 conv BN+ReLU fp32, 2 bf16 out(+bias), 3 v^T bf16 store
__global__ __launch_bounds__(256) void gemm_mfma(
    const unsigned short* __restrict__ A, const unsigned short* __restrict__ Bw,
    void* __restrict__ Cv, const float* __restrict__ bias,
    int M, int N, int K, int ldc, int epi,
    const float* __restrict__ cb, const float* __restrict__ gam,
    const float* __restrict__ bet, const float* __restrict__ mu,
    const float* __restrict__ va)
{
    __shared__ unsigned short As[4096];
    __shared__ unsigned short Bs[4096];
    const int tid = threadIdx.x, w = tid >> 6, lane = tid & 63;
    const int bm = blockIdx.y * 128, bn = blockIdx.x * 128;
    const int wr = w >> 1, wc = w & 1;

    f32x4 acc[4][4];
#pragma unroll
    for (int m = 0; m < 4; ++m)
#pragma unroll
        for (int n = 0; n < 4; ++n) acc[m][n] = (f32x4){0.f, 0.f, 0.f, 0.f};

    const int r0 = w * 16 + (lane >> 2);
    const int k8 = (lane & 3) * 8;
    const unsigned short* Ag = A + (size_t)(bm + r0) * K + k8;
    const unsigned short* Bg = Bw + (size_t)(bn + r0) * K + k8;
    unsigned short* Al = As + w * 512;
    unsigned short* Bl = Bs + w * 512;

    for (int k0 = 0; k0 < K; k0 += 32) {
        __syncthreads();
        gl_lds16(Ag + k0, Al);
        gl_lds16(Ag + (size_t)64 * K + k0, Al + 2048);
        gl_lds16(Bg + k0, Bl);
        gl_lds16(Bg + (size_t)64 * K + k0, Bl + 2048);
        __syncthreads();
        bf16x8 a[4], b[4];
#pragma unroll
        for (int m = 0; m < 4; ++m)
            a[m] = *(const bf16x8*)(As + (wr * 64 + m * 16 + (lane & 15)) * 32 + (lane >> 4) * 8);
#pragma unroll
        for (int n = 0; n < 4; ++n)
            b[n] = *(const bf16x8*)(Bs + (wc * 64 + n * 16 + (lane & 15)) * 32 + (lane >> 4) * 8);
#pragma unroll
        for (int m = 0; m < 4; ++m)
#pragma unroll
            for (int n = 0; n < 4; ++n)
                acc[m][n] = __builtin_amdgcn_mfma_f32_16x16x32_bf16(a[m], b[n], acc[m][n], 0, 0, 0);
    }

    const int cr = (lane >> 4) * 4, ccol = lane & 15;
#pragma unroll
    for (int m = 0; m < 4; ++m)
#pragma unroll
        for (int n = 0; n < 4; ++n) {
            const int col = bn + wc * 64 + n * 16 + ccol;
            const float bv = bias ? bias[col] : 0.f;
#pragma unroll
            for (int j = 0; j < 4; ++j) {
                const int row = bm + wr * 64 + m * 16 + cr + j;
                float v = acc[m][n][j] + bv;
                if (epi == 1) {
                    float x = v + cb[col];
                    v = fmaxf(0.f, gam[col] * (x - mu[col]) * rsqrtf(va[col] + 1e-5f) + bet[col]);
                }
                if (epi == 2) {
                    ((unsigned short*)Cv)[(size_t)row * ldc + col] = f2bf(v);
                } else if (epi == 3) {
                    const int bb2 = row >> 8, ss = row & 255, hh = col >> 7, dd = col & 127;
                    ((unsigned short*)Cv)[((size_t)(bb2 * 4 + hh) * 128 + dd) * 256 + ss] = f2bf(v);
                } else {
                    ((float*)Cv)[(size_t)row * ldc + col] = v;
                }
            }
        }
}

// ---------------- attention QK^T (per b,h): scores = q @ k^T * scale -------
__global__ __launch_bounds__(256) void attn_qk(
    const unsigned short* __restrict__ q, const unsigned short* __restrict__ k,
    float* __restrict__ scores)
{
    __shared__ unsigned short As[4096];
    __shared__ unsigned short Bs[4096];
    const int tid = threadIdx.x, w = tid >> 6, lane = tid & 63;
    const int bm = blockIdx.y * 128, bn = blockIdx.x * 128;
    const int z = blockIdx.z, b = z >> 2, h = z & 3;
    const int wr = w >> 1, wc = w & 1;

    const unsigned short* A  = q + ((size_t)b * T_) * 512 + h * 128;
    const unsigned short* Bw = k + ((size_t)b * S_) * 512 + h * 128;

    f32x4 acc[4][4];
#pragma unroll
    for (int m = 0; m < 4; ++m)
#pragma unroll
        for (int n = 0; n < 4; ++n) acc[m][n] = (f32x4){0.f, 0.f, 0.f, 0.f};

    const int r0 = w * 16 + (lane >> 2);
    const int k8 = (lane & 3) * 8;
    const unsigned short* Ag = A + (size_t)(bm + r0) * 512 + k8;
    const unsigned short* Bg = Bw + (size_t)(bn + r0) * 512 + k8;
    unsigned short* Al = As + w * 512;
    unsigned short* Bl = Bs + w * 512;

    for (int k0 = 0; k0 < 128; k0 += 32) {
        __syncthreads();
        gl_lds16(Ag + k0, Al);
        gl_lds16(Ag + (size_t)64 * 512 + k0, Al + 2048);
        gl_lds16(Bg + k0, Bl);
        gl_lds16(Bg + (size_t)64 * 512 + k0, Bl + 2048);
        __syncthreads();
        bf16x8 a[4], bfr[4];
#pragma unroll
        for (int m = 0; m < 4; ++m)
            a[m] = *(const bf16x8*)(As + (wr * 64 + m * 16 + (lane & 15)) * 32 + (lane >> 4) * 8);
#pragma unroll
        for (int n = 0; n < 4; ++n)
            bfr[n] = *(const bf16x8*)(Bs + (wc * 64 + n * 16 + (lane & 15)) * 32 + (lane >> 4) * 8);
#pragma unroll
        for (int m = 0; m < 4; ++m)
#pragma unroll
            for (int n = 0; n < 4; ++n)
                acc[m][n] = __builtin_amdgcn_mfma_f32_16x16x32_bf16(a[m], bfr[n], acc[m][n], 0, 0, 0);
    }

    const int cr = (lane >> 4) * 4, ccol = lane & 15;
#pragma unroll
    for (int m = 0; m < 4; ++m)
#pragma unroll
        for (int n = 0; n < 4; ++n) {
            const int col = bn + wc * 64 + n * 16 + ccol;
#pragma unroll
            for (int j = 0; j < 4; ++j) {
                const int row = bm + wr * 64 + m * 16 + cr + j;
                if (row < T_)
                    scores[((size_t)z * T_ + row) * 256 + col] = acc[m][n][j] * 0.08838834764831843f;
            }
        }
}

// ---------------- softmax over s (wave per row) ----------------------------
__global__ __launch_bounds__(256) void attn_sm(
    const float* __restrict__ scores, unsigned short* __restrict__ probs)
{
    const int row = blockIdx.x * 4 + (threadIdx.x >> 6);
    const int lane = threadIdx.x & 63;
    const float4 v = *(const float4*)(scores + (size_t)row * 256 + lane * 4);
    float m = fmaxf(fmaxf(v.x, v.y), fmaxf(v.z, v.w));
    for (int off = 32; off; off >>= 1) m = fmaxf(m, __shfl_xor(m, off));
    float ex = __expf(v.x - m), ey = __expf(v.y - m), ez = __expf(v.z - m), ew = __expf(v.w - m);
    float sum = ex + ey + ez + ew;
    for (int off = 32; off; off >>= 1) sum += __shfl_xor(sum, off);
    const float inv = 1.f / sum;
    ushort4 o;
    o.x = f2bf(ex * inv); o.y = f2bf(ey * inv); o.z = f2bf(ez * inv); o.w = f2bf(ew * inv);
    *(ushort4*)(probs + (size_t)row * 256 + lane * 4) = o;
}

// ---------------- attention PV (per b,h): ctx = probs @ vT^T ---------------
__global__ __launch_bounds__(256) void attn_pv(
    const unsigned short* __restrict__ probs, const unsigned short* __restrict__ vT,
    unsigned short* __restrict__ ctx)
{
    __shared__ unsigned short As[4096];
    __shared__ unsigned short Bs[4096];
    const int tid = threadIdx.x, w = tid >> 6, lane = tid & 63;
    const int bm = blockIdx.y * 128;
    const int z = blockIdx.z, b = z >> 2, h = z & 3;
    const int wr = w >> 1, wc = w & 1;

    const unsigned short* A  = probs + (size_t)z * T_ * 256;
    const unsigned short* Bw = vT + (size_t)z * 128 * 256;

    f32x4 acc[4][4];
#pragma unroll
    for (int m = 0; m < 4; ++m)
#pragma unroll
        for (int n = 0; n < 4; ++n) acc[m][n] = (f32x4){0.f, 0.f, 0.f, 0.f};

    const int r0 = w * 16 + (lane >> 2);
    const int k8 = (lane & 3) * 8;
    const unsigned short* Ag = A + (size_t)(bm + r0) * 256 + k8;
    const unsigned short* Bg = Bw + (size_t)r0 * 256 + k8;
    unsigned short* Al = As + w * 512;
    unsigned short* Bl = Bs + w * 512;

    for (int k0 = 0; k0 < 256; k0 += 32) {
        __syncthreads();
        gl_lds16(Ag + k0, Al);
        gl_lds16(Ag + (size_t)64 * 256 + k0, Al + 2048);
        gl_lds16(Bg + k0, Bl);
        gl_lds16(Bg + (size_t)64 * 256 + k0, Bl + 2048);
        __syncthreads();
        bf16x8 a[4], bfr[4];
#pragma unroll
        for (int m = 0; m < 4; ++m)
            a[m] = *(const bf16x8*)(As + (wr * 64 + m * 16 + (lane & 15)) * 32 + (lane >> 4) * 8);
#pragma unroll
        for (int n = 0; n < 4; ++n)
            bfr[n] = *(const bf16x8*)(Bs + (wc * 64 + n * 16 + (lane & 15)) * 32 + (lane >> 4) * 8);
#pragma unroll
        for (int m = 0; m < 4; ++m)
#pragma unroll
            for (int n = 0; n < 4; ++n)
                acc[m][n] = __builtin_amdgcn_mfma_f32_16x16x32_bf16(a[m], bfr[n], acc[m][n], 0, 0, 0);
    }

    const int cr = (lane >> 4) * 4, ccol = lane & 15;
#pragma unroll
    for (int m = 0; m < 4; ++m)
#pragma unroll
        for (int n = 0; n < 4; ++n) {
            const int col = wc * 64 + n * 16 + ccol;   // d in [0,128)
#pragma unroll
            for (int j = 0; j < 4; ++j) {
                const int row = bm + wr * 64 + m * 16 + cr + j;
                if (row < T_)
                    ctx[((size_t)b * T_ + row) * 512 + h * 128 + col] = f2bf(acc[m][n][j]);
            }
        }
}

// ---------------- fp32 tiled GEMM (mel head, N=80) --------------------------
__global__ __launch_bounds__(256) void gemm_tile(
    const float* __restrict__ A, int lda,
    const float* __restrict__ Bw,
    const float* __restrict__ bias,
    float* __restrict__ C, int ldc,
    int M, int N, int K)
{
    __shared__ float As[16][68];
    __shared__ float Bs[16][68];
    const int tid = threadIdx.x;
    const int bm = blockIdx.y * 64, bn = blockIdx.x * 64;
    const int tx = tid & 15, ty = tid >> 4;
    const int lr = tid >> 2, lk = (tid & 3) * 4;

    float acc[4][4] = {};

    const float* Aptr = A + (size_t)(bm + lr) * lda + lk;
    const bool bvalid = (bn + lr) < N;
    const float* Bptr = Bw + (size_t)(bvalid ? (bn + lr) : 0) * K + lk;

    for (int k0 = 0; k0 < K; k0 += 16) {
        float4 av = *(const float4*)(Aptr + k0);
        float4 bw = bvalid ? *(const float4*)(Bptr + k0) : make_float4(0.f, 0.f, 0.f, 0.f);
        As[lk + 0][lr] = av.x; As[lk + 1][lr] = av.y; As[lk + 2][lr] = av.z; As[lk + 3][lr] = av.w;
        Bs[lk + 0][lr] = bw.x; Bs[lk + 1][lr] = bw.y; Bs[lk + 2][lr] = bw.z; Bs[lk + 3][lr] = bw.w;
        __syncthreads();
#pragma unroll
        for (int k = 0; k < 16; ++k) {
            float4 a = *(const float4*)&As[k][ty * 4];
            float4 b = *(const float4*)&Bs[k][tx * 4];
            acc[0][0] += a.x * b.x; acc[0][1] += a.x * b.y; acc[0][2] += a.x * b.z; acc[0][3] += a.x * b.w;
            acc[1][0] += a.y * b.x; acc[1][1] += a.y * b.y; acc[1][2] += a.y * b.z; acc[1][3] += a.y * b.w;
            acc[2][0] += a.z * b.x; acc[2][1] += a.z * b.y; acc[2][2] += a.z * b.z; acc[2][3] += a.z * b.w;
            acc[3][0] += a.w * b.x; acc[3][1] += a.w * b.y; acc[3][2] += a.w * b.z; acc[3][3] += a.w * b.w;
        }
        __syncthreads();
    }

    const int row0 = bm + ty * 4, col0 = bn + tx * 4;
#pragma unroll
    for (int i = 0; i < 4; ++i)
#pragma unroll
        for (int j = 0; j < 4; ++j) {
            int cc = col0 + j;
            if (cc < N) {
                float v = acc[i][j];
                if (bias) v += bias[cc];
                C[(size_t)(row0 + i) * ldc + cc] = v;
            }
        }
}

// ---------------- elementwise / conversion kernels -------------------------
__global__ void embed_k(const int* __restrict__ txt, const float* __restrict__ emb,
                        float* __restrict__ xs)
{
    int idx = blockIdx.x * 256 + threadIdx.x;
    if (idx >= B_ * S_ * D_) return;
    int bs = idx >> 9, dd = idx & 511;
    xs[idx] = emb[(size_t)txt[bs] * D_ + dd];
}

__global__ void im2col_bf(const float* __restrict__ in, unsigned short* __restrict__ out)
{
    int idx = blockIdx.x * 256 + threadIdx.x;
    if (idx >= B_ * S_ * 2560) return;
    int r = idx / 2560, cc = idx % 2560;
    int din = cc / 5, kk = cc % 5;
    int b = r >> 8, s = r & 255;
    int sp = s + kk - 2;
    float v = (sp >= 0 && sp < S_) ? in[((size_t)b * S_ + sp) * D_ + din] : 0.f;
    out[idx] = f2bf(v);
}

__global__ void transp_bf(const float* __restrict__ in, unsigned short* __restrict__ out)
{
    int idx = blockIdx.x * 256 + threadIdx.x;
    if (idx >= B_ * S_ * D_) return;
    int d = idx & 511;
    int sb = idx >> 9;
    int s = sb >> 4, b = sb & 15;
    out[idx] = f2bf(in[((size_t)b * S_ + s) * D_ + d]);
}

__global__ void cvt_bf(const float* __restrict__ in, unsigned short* __restrict__ out,
                       int rows, int Kin, int Kout)
{
    int idx = blockIdx.x * 256 + threadIdx.x;
    if (idx >= rows * Kout) return;
    int r = idx / Kout, k = idx - r * Kout;
    out[idx] = (k < Kin) ? f2bf(in[(size_t)r * Kin + k]) : 0;
}

__global__ void cvt_w1(const float* __restrict__ W, unsigned short* __restrict__ out)
{
    int idx = blockIdx.x * 256 + threadIdx.x;
    if (idx >= 3072 * 608) return;
    int n = idx / 608, k = idx - n * 608;
    int orig = (n < 1024) ? n : n + 1024;
    out[idx] = (k < 592) ? f2bf(W[(size_t)orig * 592 + k]) : 0;
}

__global__ void cvt_w2(const float* __restrict__ W, unsigned short* __restrict__ out)
{
    int idx = blockIdx.x * 256 + threadIdx.x;
    if (idx >= 3072 * 1024) return;
    int n = idx >> 10, k = idx & 1023;
    int orig = (n < 1024) ? n : n + 1024;
    out[idx] = f2bf(W[(size_t)orig * 1024 + k]);
}

__global__ void decin_k2(const float* __restrict__ mel, unsigned short* __restrict__ din,
                         unsigned short* __restrict__ xcat)
{
    int idx = blockIdx.x * 256 + threadIdx.x;
    if (idx >= B_ * T_ * 96) return;
    int r = idx / 96, j = idx - r * 96;
    int b = r / T_, t = r - b * T_;
    float v = (j < M_ && t > 0) ? mel[((size_t)b * T_ + t - 1) * M_ + j] : 0.f;
    unsigned short bv = f2bf(v);
    din[(size_t)r * 96 + j] = bv;
    xcat[(size_t)r * 608 + 512 + j] = bv;
}

__global__ void dec_cell1(const float* __restrict__ g, const float* __restrict__ b1,
                          unsigned short* __restrict__ h, int rows)
{
    int idx = blockIdx.x * 256 + threadIdx.x;
    if (idx >= rows * H_) return;
    int r = idx >> 10, j = idx & 1023;
    const float* gr = g + (size_t)r * 3072;
    float ig = sigf(gr[j] + b1[j]);
    float gg = tanhfast(gr[1024 + j] + b1[2048 + j]);
    float og = sigf(gr[2048 + j] + b1[3072 + j]);
    h[idx] = f2bf(og * tanhfast(ig * gg));
}

__global__ void dec_cell2(const float* __restrict__ g, const float* __restrict__ b2,
                          float* __restrict__ h, int rows)
{
    int idx = blockIdx.x * 256 + threadIdx.x;
    if (idx >= rows * H_) return;
    int r = idx >> 10, j = idx & 1023;
    const float* gr = g + (size_t)r * 3072;
    float ig = sigf(gr[j] + b2[j]);
    float gg = tanhfast(gr[1024 + j] + b2[2048 + j]);
    float og = sigf(gr[2048 + j] + b2[3072 + j]);
    h[idx] = og * tanhfast(ig * gg);
}

__global__ __launch_bounds__(256) void stop_head(
    const float* __restrict__ h2, const float* __restrict__ sw,
    const float* __restrict__ sb, float* __restrict__ out)
{
    int row = blockIdx.x * 4 + (threadIdx.x >> 6);
    int lane = threadIdx.x & 63;
    const float* hr = h2 + (size_t)row * H_;
    float acc = 0.f;
#pragma unroll
    for (int i = 0; i < H_; i += 64) acc += hr[i + lane] * sw[i + lane];
    for (int off = 32; off; off >>= 1) acc += __shfl_xor(acc, off);
    if (lane == 0) out[row] = acc + sb[0];
}

// ---------------- persistent LSTM: 2 blocks per direction ------------------
// Block = (dir, half): owns hidden units [half*128, half*128+128) and their
// 4 gates = 512 W-rows, held in VGPRs as f16 MFMA B-fragments (64 VGPR/lane).
// Per step: 16 MFMA/wave -> LDS gate exchange -> 1024 threads update 2
// (hid,batch) pairs -> 4KB partner-h exchange via LLC, 2-block barrier.
__global__ __launch_bounds__(1024) void lstm_persist2(
    const float* __restrict__ gi_f, const float* __restrict__ gi_b,
    const float* __restrict__ Wf, const float* __restrict__ Wb,
    unsigned short* __restrict__ enc,     // bf16 (B,S,512)
    _Float16* __restrict__ hstage,        // [2][16][256]
    int* __restrict__ cnt)                // [2][256]
{
    const int blk = blockIdx.x;
    const int dir = blk >> 1, half = blk & 1;
    const float* gi = dir ? gi_b : gi_f;
    const float* W  = dir ? Wb : Wf;
    const int tid = threadIdx.x, wv = tid >> 6, lane = tid & 63;
    const int l15 = lane & 15, q = lane >> 4;

    __shared__ _Float16 h_lds[16][264];   // [batch][hid 0..255], pad 8
    __shared__ float exch[512][17];       // [gate*128+hid_local][batch], pad 1

    // --- preload W fragments: wave wv owns tiles wv and wv+16 ---
    half8 w0[8], w1[8];
    {
        const int gt0 = wv >> 3, hb0 = wv & 7;          // tile wv
        const int gt1 = (wv + 16) >> 3;                 // tile wv+16 (same hb)
        const float* wr0 = W + (size_t)(gt0 * 256 + half * 128 + hb0 * 16 + l15) * 256;
        const float* wr1 = W + (size_t)(gt1 * 256 + half * 128 + hb0 * 16 + l15) * 256;
#pragma unroll
        for (int ks = 0; ks < 8; ++ks) {
            half8 a, b;
#pragma unroll
            for (int j = 0; j < 8; ++j) {
                a[j] = (_Float16)wr0[ks * 32 + q * 8 + j];
                b[j] = (_Float16)wr1[ks * 32 + q * 8 + j];
            }
            w0[ks] = a; w1[ks] = b;
        }
    }
    for (int i = tid; i < 16 * 264; i += 1024) ((_Float16*)h_lds)[i] = (_Float16)0.f;

    // update mapping: pair0 = (ba, hid), pair1 = (ba+8, hid)
    const int hid = tid & 127;
    const int ba  = tid >> 7;       // 0..7
    const int bb  = ba + 8;
    const int gh  = half * 128 + hid;
    float c0 = 0.f, c1 = 0.f;

    const int exr0 = (wv >> 3) * 128 + (wv & 7) * 16 + l15;
    const int exr1 = ((wv + 16) >> 3) * 128 + (wv & 7) * 16 + l15;

    // partner-read mapping
    const int pb = tid >> 6;                    // batch 0..15
    const int px = (half ^ 1) * 128 + (tid & 63) * 2;

    int* mycnt = cnt + dir * 256;

    // gi prefetch for step 0
    float gp0[4], gp1[4];
    {
        const int s0 = dir ? 255 : 0;
        const float* g0 = gi + ((size_t)s0 * 16 + ba) * 1024 + gh;
        const float* g1 = gi + ((size_t)s0 * 16 + bb) * 1024 + gh;
#pragma unroll
        for (int g2 = 0; g2 < 4; ++g2) { gp0[g2] = g0[g2 * 256]; gp1[g2] = g1[g2 * 256]; }
    }
    __syncthreads();

    for (int step = 0; step < 256; ++step) {
        const int s = dir ? (255 - step) : step;

        f32x4 acc0 = (f32x4){0.f, 0.f, 0.f, 0.f};
        f32x4 acc1 = (f32x4){0.f, 0.f, 0.f, 0.f};
#pragma unroll
        for (int ks = 0; ks < 8; ++ks) {
            half8 a = *(const half8*)&h_lds[l15][ks * 32 + q * 8];
            acc0 = __builtin_amdgcn_mfma_f32_16x16x32_f16(a, w0[ks], acc0, 0, 0, 0);
            acc1 = __builtin_amdgcn_mfma_f32_16x16x32_f16(a, w1[ks], acc1, 0, 0, 0);
        }
        *(f32x4*)&exch[exr0][q * 4] = acc0;
        *(f32x4*)&exch[exr1][q * 4] = acc1;
        __syncthreads();

        // ---- c/h update: 2 pairs per thread ----
        float h0, h1;
        {
            float xi = exch[hid][ba] + gp0[0];
            float xf = exch[128 + hid][ba] + gp0[1];
            float xg = exch[256 + hid][ba] + gp0[2];
            float xo = exch[384 + hid][ba] + gp0[3];
            float ig = sigf(xi), fg = sigf(xf), gg = tanhfast(xg), og = sigf(xo);
            c0 = fg * c0 + ig * gg; h0 = og * tanhfast(c0);
            xi = exch[hid][bb] + gp1[0];
            xf = exch[128 + hid][bb] + gp1[1];
            xg = exch[256 + hid][bb] + gp1[2];
            xo = exch[384 + hid][bb] + gp1[3];
            ig = sigf(xi); fg = sigf(xf); gg = tanhfast(xg); og = sigf(xo);
            c1 = fg * c1 + ig * gg; h1 = og * tanhfast(c1);
        }
        h_lds[ba][gh] = (_Float16)h0;
        h_lds[bb][gh] = (_Float16)h1;
        hstage[((size_t)dir * 16 + ba) * 256 + gh] = (_Float16)h0;
        hstage[((size_t)dir * 16 + bb) * 256 + gh] = (_Float16)h1;
        enc[((size_t)ba * S_ + s) * 512 + dir * 256 + gh] = f2bf(h0);
        enc[((size_t)bb * S_ + s) * 512 + dir * 256 + gh] = f2bf(h1);

        // ---- prefetch next-step gi (independent of barrier) ----
        if (step < 255) {
            const int s2 = dir ? (254 - step) : (step + 1);
            const float* g0 = gi + ((size_t)s2 * 16 + ba) * 1024 + gh;
            const float* g1 = gi + ((size_t)s2 * 16 + bb) * 1024 + gh;
#pragma unroll
            for (int g2 = 0; g2 < 4; ++g2) { gp0[g2] = g0[g2 * 256]; gp1[g2] = g1[g2 * 256]; }
        }

        // ---- 2-block barrier (per-step slot) ----
        if (tid == 0) {
            __threadfence();
            __hip_atomic_fetch_add(&mycnt[step], 1, __ATOMIC_RELEASE, __HIP_MEMORY_SCOPE_AGENT);
            while (__hip_atomic_load(&mycnt[step], __ATOMIC_ACQUIRE, __HIP_MEMORY_SCOPE_AGENT) < 2)
                __builtin_amdgcn_s_sleep(1);
        }
        __syncthreads();
        __threadfence();
        // ---- read partner half into LDS ----
        {
            unsigned int v2 = *(const unsigned int*)&hstage[((size_t)dir * 16 + pb) * 256 + px];
            *(unsigned int*)&h_lds[pb][px] = v2;
        }
        __syncthreads();
    }
}

// ---------------- host orchestration --------------------------------------
static inline void launch_mfma(hipStream_t st, const unsigned short* A, const unsigned short* B,
                               void* C, const float* bias, int M, int N, int K, int ldc, int epi = 0,
                               const float* cb = nullptr, const float* gam = nullptr,
                               const float* bet = nullptr, const float* mu = nullptr,
                               const float* va = nullptr)
{
    dim3 grid(N / 128, M / 128);
    gemm_mfma<<<grid, 256, 0, st>>>(A, B, C, bias, M, N, K, ldc, epi, cb, gam, bet, mu, va);
}

extern "C" void kernel_launch(void* const* d_in, const int* in_sizes, int n_in,
                              void* d_out, int out_size, void* d_ws, size_t ws_size,
                              hipStream_t stream)
{
    const int*   text   = (const int*)d_in[0];
    const float* mel_t  = (const float*)d_in[1];
    const float* emb    = (const float*)d_in[2];
    const float* conv_w = (const float*)d_in[3];
    const float* conv_b = (const float*)d_in[4];
    const float* bn_g   = (const float*)d_in[5];
    const float* bn_b   = (const float*)d_in[6];
    const float* bn_m   = (const float*)d_in[7];
    const float* bn_v   = (const float*)d_in[8];
    const float* Wih_f  = (const float*)d_in[9];
    const float* Whh_f  = (const float*)d_in[10];
    const float* b_f    = (const float*)d_in[11];
    const float* Wih_b  = (const float*)d_in[12];
    const float* Whh_b  = (const float*)d_in[13];
    const float* b_b    = (const float*)d_in[14];
    const float* Wq     = (const float*)d_in[15];
    const float* bq     = (const float*)d_in[16];
    const float* Wk     = (const float*)d_in[17];
    const float* bk     = (const float*)d_in[18];
    const float* Wv     = (const float*)d_in[19];
    const float* bv     = (const float*)d_in[20];
    const float* Wo     = (const float*)d_in[21];
    const float* bo     = (const float*)d_in[22];
    const float* Wih1   = (const float*)d_in[23];
    const float* b1     = (const float*)d_in[24];
    const float* Wih2   = (const float*)d_in[25];
    const float* b2     = (const float*)d_in[26];
    const float* melW   = (const float*)d_in[27];
    const float* melb   = (const float*)d_in[28];
    const float* stopW  = (const float*)d_in[29];
    const float* stopb  = (const float*)d_in[30];
    float* out = (float*)d_out;
    (void)in_sizes; (void)n_in; (void)out_size; (void)ws_size;

    float* ws = (float*)d_ws;
    float* big  = ws;                       // 13107200 f: im2col | scores fp32 | h2
    float* pool = ws + 13107200;

    int*      cnt    = (int*)(ws + 6000000);            // [2][256] (inside big, quiet window)
    _Float16* hstage = (_Float16*)(ws + 6000000 + 512); // [2][16][256]

    // phase A/B (encoder)
    float*          gi_f   = pool + 0;
    float*          gi_b   = pool + 4194304;
    unsigned short* enc_bf = (unsigned short*)(pool + 8388608);
    float*          P0     = pool + 9437184;
    float*          P1     = pool + 11534336;
    unsigned short* xsT    = (unsigned short*)(pool + 13631488);
    // phase C (attention)
    unsigned short* kbf    = (unsigned short*)(pool + 0);          // 4096x512
    unsigned short* vT     = (unsigned short*)(pool + 1048576);    // 64x128x256
    unsigned short* qbf    = (unsigned short*)(pool + 2097152);    // 12928x512 (pad rows)
    unsigned short* probs  = (unsigned short*)(pool + 9437184);    // 51328x256 (pad rows)
    unsigned short* dinb   = (unsigned short*)(pool + 16008192);   // 12800x96
    unsigned short* ctxb   = (unsigned short*)(pool + 16622592);   // 12800x512
    // phase D (decoder)
    float*          gates  = pool + 0;                             // 3200x3072
    unsigned short* h1b    = (unsigned short*)(pool + 9830400);    // 12800x1024
    unsigned short* xcat   = (unsigned short*)(pool + 19899392);   // 12800x608
    // weights
    float*          WB     = pool + 23790592;
    unsigned short* cWc  = (unsigned short*)(WB + 0);
    unsigned short* cWif = (unsigned short*)(WB + 1966080);
    unsigned short* cWib = (unsigned short*)(WB + 2228224);
    unsigned short* cWk  = (unsigned short*)(WB + 2490368);
    unsigned short* cWv  = (unsigned short*)(WB + 2621440);
    unsigned short* cWq  = (unsigned short*)(WB + 2752512);
    unsigned short* cWo  = (unsigned short*)(WB + 2777088);
    unsigned short* cW1  = (unsigned short*)(WB + 2908160);
    unsigned short* cW2  = (unsigned short*)(WB + 3842048);

    auto ceil256 = [](int n) { return (n + 255) / 256; };

    hipMemsetAsync(cnt, 0, 512 * 4, stream);

    // ---- weight conversions ----
    cvt_bf<<<ceil256(1536 * 2560), 256, 0, stream>>>(conv_w, cWc, 1536, 2560, 2560);
    cvt_bf<<<ceil256(1024 * 512), 256, 0, stream>>>(Wih_f, cWif, 1024, 512, 512);
    cvt_bf<<<ceil256(1024 * 512), 256, 0, stream>>>(Wih_b, cWib, 1024, 512, 512);
    cvt_bf<<<ceil256(512 * 512), 256, 0, stream>>>(Wk, cWk, 512, 512, 512);
    cvt_bf<<<ceil256(512 * 512), 256, 0, stream>>>(Wv, cWv, 512, 512, 512);
    cvt_bf<<<ceil256(512 * 96), 256, 0, stream>>>(Wq, cWq, 512, 80, 96);
    cvt_bf<<<ceil256(512 * 512), 256, 0, stream>>>(Wo, cWo, 512, 512, 512);
    cvt_w1<<<ceil256(3072 * 608), 256, 0, stream>>>(Wih1, cW1);
    cvt_w2<<<ceil256(3072 * 1024), 256, 0, stream>>>(Wih2, cW2);

    // ---- encoder: embedding + 3 convs ----
    embed_k<<<ceil256(B_ * S_ * D_), 256, 0, stream>>>(text, emb, P0);
    float* cin = P0;
    float* cout = P1;
    for (int l = 0; l < 3; ++l) {
        im2col_bf<<<ceil256(B_ * S_ * 2560), 256, 0, stream>>>(cin, (unsigned short*)big);
        launch_mfma(stream, (unsigned short*)big, cWc + (size_t)l * 512 * 2560,
                    cout, nullptr, B_ * S_, 512, 2560, 512, 1,
                    conv_b + l * 512, bn_g + l * 512, bn_b + l * 512, bn_m + l * 512, bn_v + l * 512);
        float* tmp = cin; cin = cout; cout = tmp;
    }
    transp_bf<<<ceil256(B_ * S_ * D_), 256, 0, stream>>>(cin, xsT);

    // ---- encoder LSTM ----
    launch_mfma(stream, xsT, cWif, gi_f, b_f, S_ * B_, 1024, 512, 1024);
    launch_mfma(stream, xsT, cWib, gi_b, b_b, S_ * B_, 1024, 512, 1024);
    lstm_persist2<<<4, 1024, 0, stream>>>(gi_f, gi_b, Whh_f, Whh_b, enc_bf, hstage, cnt);

    // ---- attention projections (bf16 outputs; v stored transposed) ----
    launch_mfma(stream, enc_bf, cWk, kbf, bk, B_ * S_, 512, 512, 512, 2);
    launch_mfma(stream, enc_bf, cWv, vT, bv, B_ * S_, 512, 512, 0, 3);
    decin_k2<<<ceil256(B_ * T_ * 96), 256, 0, stream>>>(mel_t, dinb, xcat);
    launch_mfma(stream, dinb, cWq, qbf, bq, B_ * T_, 512, 96, 512, 2);

    // ---- attention: MFMA scores -> softmax -> MFMA PV ----
    attn_qk<<<dim3(2, 7, 64), 256, 0, stream>>>(qbf, kbf, big);
    attn_sm<<<12800, 256, 0, stream>>>(big, probs);
    attn_pv<<<dim3(1, 7, 64), 256, 0, stream>>>(probs, vT, ctxb);

    // ---- Wo projection -> xcat[:, 0:512) bf16 ----
    launch_mfma(stream, ctxb, cWo, xcat, bo, B_ * T_, 512, 512, 608, 2);

    // ---- decoder cells (f-gate dropped; N=3072 = [i;g;o]) ----
    float* h2 = big;
    const int MC = 3200;
    for (int c0 = 0; c0 < B_ * T_; c0 += MC) {
        launch_mfma(stream, xcat + (size_t)c0 * 608, cW1, gates, nullptr, MC, 3072, 608, 3072);
        dec_cell1<<<ceil256(MC * H_), 256, 0, stream>>>(gates, b1, h1b + (size_t)c0 * H_, MC);
    }
    for (int c0 = 0; c0 < B_ * T_; c0 += MC) {
        launch_mfma(stream, h1b + (size_t)c0 * H_, cW2, gates, nullptr, MC, 3072, 1024, 3072);
        dec_cell2<<<ceil256(MC * H_), 256, 0, stream>>>(gates, b2, h2 + (size_t)c0 * H_, MC);
    }

    // ---- output heads ----
    {
        dim3 grid((80 + 63) / 64, (B_ * T_) / 64);
        gemm_tile<<<grid, 256, 0, stream>>>(h2, 1024, melW, melb, out, 80, B_ * T_, 80, 1024);
    }
    stop_head<<<(B_ * T_) / 4, 256, 0, stream>>>(h2, stopW, stopb, out + (size_t)B_ * T_ * M_);
}